// Round 10
// baseline (278.004 us; speedup 1.0000x reference)
//
#include <hip/hip_runtime.h>
#include <math.h>

// Problem constants
#define TT 4096
#define DD 512
#define RR 32
#define CC 32
#define RC 1024
#define LL 2
#define CHUNK 32
#define NCHUNK 128
#define NEG_SLOPE 0.01f
#define LN_EPS 1e-5f

typedef __attribute__((ext_vector_type(8))) __bf16 bf16x8;
typedef __attribute__((ext_vector_type(4))) float f32x4;

__device__ __forceinline__ unsigned short f2bf(float f) {
    unsigned int u = __builtin_bit_cast(unsigned int, f);
    u += 0x7fffu + ((u >> 16) & 1u);   // round-to-nearest-even
    return (unsigned short)(u >> 16);
}

// async global->LDS, 16B per lane; LDS dest = wave-uniform base + lane*16
__device__ __forceinline__ void gload16(const unsigned short* g, unsigned short* l) {
    __builtin_amdgcn_global_load_lds(
        (const __attribute__((address_space(1))) unsigned int*)(const void*)g,
        (__attribute__((address_space(3))) unsigned int*)(void*)l,
        16, 0, 0);
}

// ---------------------------------------------------------------------------
// Fused setup: f32->bf16 for x, W0, W1, plus Wt/Wc pack into Wtc[L,64,512].
#define NX4  524288   // 4096*512/4
#define NW04 524288   // 2*512*2048/4
#define NW14 131072   // 2*512*512/4
#define NCV  (NX4 + NW04 + NW14)
#define NPK  16384    // 2*64*512/4
__global__ __launch_bounds__(256) void setup_kernel(const float4* __restrict__ x,
                                                    const float4* __restrict__ W0,
                                                    const float4* __restrict__ W1,
                                                    const float* __restrict__ Wt,
                                                    const float* __restrict__ Wc,
                                                    ushort4* __restrict__ xb,
                                                    ushort4* __restrict__ W0b,
                                                    ushort4* __restrict__ W1b,
                                                    ushort4* __restrict__ Wtc) {
    int i = blockIdx.x * 256 + threadIdx.x;
    float4 v;
    ushort4* dst;
    int j;
    if (i < NCV) {
        const float4* src;
        if (i < NX4) { src = x; dst = xb; j = i; }
        else if (i < NX4 + NW04) { src = W0; dst = W0b; j = i - NX4; }
        else { src = W1; dst = W1b; j = i - NX4 - NW04; }
        v = src[j];
    } else {
        int ii = i - NCV;
        if (ii >= NPK) return;
        int e = ii * 4;
        int l = e >> 15;
        int r = (e >> 9) & 63;
        int k = e & 511;
        v = (r < 32) ? *(const float4*)&Wt[((size_t)l * 32 + r) * 512 + k]
                     : *(const float4*)&Wc[((size_t)l * 32 + (r - 32)) * 512 + k];
        dst = Wtc; j = ii;
    }
    ushort4 o;
    o.x = f2bf(v.x); o.y = f2bf(v.y); o.z = f2bf(v.z); o.w = f2bf(v.w);
    dst[j] = o;
}

// ---------------------------------------------------------------------------
// proj + denom fused (R7 proven): tcabs[t,r]=|tr_r|*invd (r<32); tcabs[t,32+c]=|ct_c|
__global__ __launch_bounds__(256) void proj_denom_kernel(const unsigned short* __restrict__ A,
                                                         const unsigned short* __restrict__ B,
                                                         float* __restrict__ tcabs) {
    __shared__ __align__(16) unsigned short As[64 * 32];
    __shared__ __align__(16) unsigned short Bs[64 * 32];
    const int tid = threadIdx.x;
    const int w = tid >> 6, lane = tid & 63;
    const int bm = blockIdx.x * 64;
    const int K = 512;
    const int srow = tid >> 2;           // 0..63
    const int sl = tid & 3;              // 16B slot
    const int sswz = (sl ^ ((srow >> 1) & 3)) * 8;
    const unsigned short* gA = A + (size_t)(bm + srow) * K + sl * 8;
    const unsigned short* gB = B + (size_t)srow * K + sl * 8;
    const int wA = srow * 32 + sswz;
    const int wB = srow * 32 + sswz;
    const int fr = lane & 15, hi = lane >> 4;
    const int kslot = hi ^ ((fr >> 1) & 3);
    f32x4 acc0 = {}, acc1 = {}, acc2 = {}, acc3 = {};

    uint4 va = *(const uint4*)gA;
    uint4 vb = *(const uint4*)gB;
    for (int k0 = 0; k0 < K; k0 += 32) {
        __syncthreads();
        *(uint4*)&As[wA] = va;
        *(uint4*)&Bs[wB] = vb;
        __syncthreads();
        if (k0 + 32 < K) {
            va = *(const uint4*)(gA + k0 + 32);
            vb = *(const uint4*)(gB + k0 + 32);
        }
        const int arow = w * 16 + fr;
        bf16x8 af = *(const bf16x8*)&As[arow * 32 + kslot * 8];
        bf16x8 b0 = *(const bf16x8*)&Bs[(0 * 16 + fr) * 32 + kslot * 8];
        bf16x8 b1 = *(const bf16x8*)&Bs[(1 * 16 + fr) * 32 + kslot * 8];
        bf16x8 b2 = *(const bf16x8*)&Bs[(2 * 16 + fr) * 32 + kslot * 8];
        bf16x8 b3 = *(const bf16x8*)&Bs[(3 * 16 + fr) * 32 + kslot * 8];
        acc0 = __builtin_amdgcn_mfma_f32_16x16x32_bf16(af, b0, acc0, 0, 0, 0);
        acc1 = __builtin_amdgcn_mfma_f32_16x16x32_bf16(af, b1, acc1, 0, 0, 0);
        acc2 = __builtin_amdgcn_mfma_f32_16x16x32_bf16(af, b2, acc2, 0, 0, 0);
        acc3 = __builtin_amdgcn_mfma_f32_16x16x32_bf16(af, b3, acc3, 0, 0, 0);
    }
#pragma unroll
    for (int q = 0; q < 4; ++q) {
        float a0 = fabsf(acc0[q]), a1 = fabsf(acc1[q]);
        float a2 = fabsf(acc2[q]), a3 = fabsf(acc3[q]);
        float st = a0 + a1, sc = a2 + a3;
        st += __shfl_xor(st, 1); sc += __shfl_xor(sc, 1);
        st += __shfl_xor(st, 2); sc += __shfl_xor(sc, 2);
        st += __shfl_xor(st, 4); sc += __shfl_xor(sc, 4);
        st += __shfl_xor(st, 8); sc += __shfl_xor(sc, 8);
        float inv = 1.f / (1e-8f + st * sc);
        size_t rb = (size_t)(bm + w * 16 + hi * 4 + q) * 64;
        tcabs[rb + fr]      = a0 * inv;
        tcabs[rb + fr + 16] = a1 * inv;
        tcabs[rb + fr + 32] = a2;
        tcabs[rb + fr + 48] = a3;
    }
}

// ---------------------------------------------------------------------------
// Scan pass 1: per (chunk, r, c) affine transform (alpha, beta) with resets.
__global__ __launch_bounds__(256) void scan_pass1(const float* __restrict__ tcabs,
                                                  const int* __restrict__ start,
                                                  const float* __restrict__ a,
                                                  const float* __restrict__ b,
                                                  float4* __restrict__ ab4) {
    int tid = blockIdx.x * 256 + threadIdx.x;   // NCHUNK*RC = 131072
    int rc = tid & (RC - 1);
    int chunk = tid >> 10;
    int r = rc >> 5, c = rc & 31;
    float e = expf(-fabsf(a[r]));
    float gr = e * cosf(b[c]);
    float gi = e * sinf(b[c]);
    float alr = 1.f, ali = 0.f, ber = 0.f, bei = 0.f;
    int t0 = chunk * CHUNK;
    for (int j = 0; j < CHUNK; ++j) {
        int t = t0 + j;
        float pre = tcabs[t * 64 + r] * tcabs[t * 64 + 32 + c];
        if (start[t]) {
            alr = 0.f; ali = 0.f; ber = pre; bei = 0.f;
        } else {
            float nbr = pre + gr * ber - gi * bei;
            float nbi =       gr * bei + gi * ber;
            float nar = gr * alr - gi * ali;
            float nai = gr * ali + gi * alr;
            ber = nbr; bei = nbi; alr = nar; ali = nai;
        }
    }
    ab4[chunk * RC + rc] = make_float4(alr, ali, ber, bei);
}

// ---------------------------------------------------------------------------
// Scan pass 2 + in-block lookback (8-deep prefetch), emit scaled (bf16).
__global__ __launch_bounds__(256) void scan_pass2f(const float* __restrict__ tcabs,
                                                   const float4* __restrict__ ab4,
                                                   const int* __restrict__ start,
                                                   const float* __restrict__ a,
                                                   const float* __restrict__ b,
                                                   const float* __restrict__ s0r,
                                                   const float* __restrict__ s0i,
                                                   unsigned short* __restrict__ scaled) {
    int bx = blockIdx.x;
    int chunk = bx >> 2;
    int rc = (bx & 3) * 256 + threadIdx.x;
    int r = rc >> 5, c = rc & 31;
    float e = expf(-fabsf(a[r]));
    float gr = e * cosf(b[c]);
    float gi = e * sinf(b[c]);
    float sr = s0r[rc], si = s0i[rc];
    int j = 0;
    for (; j + 8 <= chunk; j += 8) {
        float4 buf[8];
#pragma unroll
        for (int u = 0; u < 8; ++u) buf[u] = ab4[(j + u) * RC + rc];
#pragma unroll
        for (int u = 0; u < 8; ++u) {
            float nsr = buf[u].z + buf[u].x * sr - buf[u].y * si;
            float nsi = buf[u].w + buf[u].x * si + buf[u].y * sr;
            sr = nsr; si = nsi;
        }
    }
    for (; j < chunk; ++j) {
        float4 ab = ab4[j * RC + rc];
        float nsr = ab.z + ab.x * sr - ab.y * si;
        float nsi = ab.w + ab.x * si + ab.y * sr;
        sr = nsr; si = nsi;
    }
    int t0 = chunk * CHUNK;
    for (int jj = 0; jj < CHUNK; ++jj) {
        int t = t0 + jj;
        float pre = tcabs[t * 64 + r] * tcabs[t * 64 + 32 + c];
        if (start[t]) {
            sr = pre; si = 0.f;
        } else {
            float nsr = pre + gr * sr - gi * si;
            float nsi =       gr * si + gi * sr;
            sr = nsr; si = nsi;
        }
        float m = sqrtf(sr * sr + si * si);
        float mag = log1pf(m);
        float f = (m > 0.f) ? (mag / m) : 0.f;
        scaled[(size_t)t * 2048 + rc]        = f2bf(si * f);
        scaled[(size_t)t * 2048 + 1024 + rc] = f2bf(sr * f);
    }
}

// ---------------------------------------------------------------------------
// Fused GEMM + bias + LayerNorm + LeakyReLU.
// C-tile 16(M) x 512(full N): grid 256 blocks (M=4096/16), 4 waves, each wave
// owns 128 cols (8 frags of 16x16x32, acc=32 VGPR). B (weights, <=2MB bf16)
// staged to LDS per K-step (32KB) via global_load_lds, double-buffered
// (issue next step's loads before current MFMA; one barrier/step).
// Swizzle: LDS linear, global source slot pre-swizzled (R9-verified scheme);
// read kslot = hi ^ ((fr>>1)&3) — conflict-free.
// Epilogue: per-row sum/sumsq (in-reg + shfl_xor over fr + [16][4] LDS cross-
// wave) -> LN -> LeakyReLU -> optional bf16 z / residual bf16 h / f32 out.
template <int K>
__global__ __launch_bounds__(256) void gemm_ln(const unsigned short* __restrict__ A,
                                               const unsigned short* __restrict__ B,
                                               const float* __restrict__ bias,
                                               const float* __restrict__ g,
                                               const float* __restrict__ be,
                                               unsigned short* __restrict__ zb,
                                               const float* __restrict__ res,
                                               unsigned short* __restrict__ hbf,
                                               float* __restrict__ fout) {
    __shared__ __align__(16) unsigned short As[2][16 * 32];
    __shared__ __align__(16) unsigned short Bs[2][512 * 32];
    __shared__ float smem_s[16][4];
    __shared__ float smem_ss[16][4];
    const int tid = threadIdx.x;
    const int w = tid >> 6, lane = tid & 63;
    const int bm = blockIdx.x * 16;
    const int fr = lane & 15, hi = lane >> 4;
    const int kslot = hi ^ ((fr >> 1) & 3);
    // staging: lane covers (row, phys slot); source uses swizzled logical slot.
    const int srow = lane >> 2;                       // 0..15
    const int slog = (lane & 3) ^ ((srow >> 1) & 3);  // u/w-invariant here
    const unsigned short* gBb = B + (size_t)(w * 16 + srow) * K + slog * 8;
    const unsigned short* gAb = A + (size_t)(bm + srow) * K + slog * 8;

    f32x4 acc[8] = {};
    constexpr int NT = K / 32;

    // prologue: stage tile 0 into buffer 0
#pragma unroll
    for (int u = 0; u < 8; ++u)
        gload16(gBb + (size_t)u * 64 * K, &Bs[0][(size_t)w * 512 + u * 2048]);
    if (w == 0) gload16(gAb, &As[0][0]);
    __syncthreads();
    int cur = 0;
    for (int t = 0; t < NT; ++t) {
        if (t + 1 < NT) {  // issue next tile's loads (other buffer) first
            const int k0n = (t + 1) * 32;
            unsigned short* bd = &Bs[cur ^ 1][(size_t)w * 512];
#pragma unroll
            for (int u = 0; u < 8; ++u)
                gload16(gBb + (size_t)u * 64 * K + k0n, bd + u * 2048);
            if (w == 0) gload16(gAb + k0n, &As[cur ^ 1][0]);
        }
        bf16x8 af = *(const bf16x8*)&As[cur][fr * 32 + kslot * 8];
#pragma unroll
        for (int nf = 0; nf < 8; ++nf) {
            int col = w * 128 + nf * 16 + fr;
            bf16x8 bv = *(const bf16x8*)&Bs[cur][col * 32 + kslot * 8];
            acc[nf] = __builtin_amdgcn_mfma_f32_16x16x32_bf16(af, bv, acc[nf], 0, 0, 0);
        }
        __syncthreads();   // drains this step's issued loads; frees buf cur
        cur ^= 1;
    }

    // epilogue: LN over full rows (each wave holds 128 of the 512 cols)
    float bs[8], gs[8], bes[8];
#pragma unroll
    for (int nf = 0; nf < 8; ++nf) {
        int col = w * 128 + nf * 16 + fr;
        bs[nf] = bias[col]; gs[nf] = g[col]; bes[nf] = be[col];
    }
#pragma unroll
    for (int q = 0; q < 4; ++q) {
        float s = 0.f, ss = 0.f;
#pragma unroll
        for (int nf = 0; nf < 8; ++nf) {
            float v = acc[nf][q] + bs[nf];
            s += v; ss += v * v;
        }
        s += __shfl_xor(s, 1); ss += __shfl_xor(ss, 1);
        s += __shfl_xor(s, 2); ss += __shfl_xor(ss, 2);
        s += __shfl_xor(s, 4); ss += __shfl_xor(ss, 4);
        s += __shfl_xor(s, 8); ss += __shfl_xor(ss, 8);
        if (fr == 0) { smem_s[hi * 4 + q][w] = s; smem_ss[hi * 4 + q][w] = ss; }
    }
    __syncthreads();
#pragma unroll
    for (int q = 0; q < 4; ++q) {
        int row = hi * 4 + q;
        float S  = smem_s[row][0] + smem_s[row][1] + smem_s[row][2] + smem_s[row][3];
        float SS = smem_ss[row][0] + smem_ss[row][1] + smem_ss[row][2] + smem_ss[row][3];
        float m = S * (1.f / 512.f);
        float rs = rsqrtf(SS * (1.f / 512.f) - m * m + LN_EPS);
        size_t rb = (size_t)(bm + row) * 512;
#pragma unroll
        for (int nf = 0; nf < 8; ++nf) {
            int col = w * 128 + nf * 16 + fr;
            float v = acc[nf][q] + bs[nf];
            float z = gs[nf] * (v - m) * rs + bes[nf];
            z = (z > 0.f) ? z : NEG_SLOPE * z;
            if (zb)   zb[rb + col] = f2bf(z);
            if (hbf)  hbf[rb + col] = f2bf(res[rb + col] + z);
            if (fout) fout[rb + col] = z;
        }
    }
}

// ---------------------------------------------------------------------------
extern "C" void kernel_launch(void* const* d_in, const int* in_sizes, int n_in,
                              void* d_out, int out_size, void* d_ws, size_t ws_size,
                              hipStream_t stream) {
    const float* x     = (const float*)d_in[0];
    const int*   start = (const int*)d_in[1];
    const float* s0r = (const float*)d_in[3];
    const float* s0i = (const float*)d_in[4];
    const float* Wt  = (const float*)d_in[5];
    const float* Wc  = (const float*)d_in[6];
    const float* a   = (const float*)d_in[7];
    const float* b   = (const float*)d_in[8];
    const float* W0  = (const float*)d_in[9];
    const float* b0  = (const float*)d_in[10];
    const float* g0  = (const float*)d_in[11];
    const float* be0 = (const float*)d_in[12];
    const float* W1  = (const float*)d_in[13];
    const float* b1  = (const float*)d_in[14];
    const float* g1  = (const float*)d_in[15];
    const float* be1 = (const float*)d_in[16];
    float* out = (float*)d_out;
    float* ws  = (float*)d_ws;

    // workspace layout (float-unit offsets, all 16B aligned)  ~38 MB
    float* p = ws;
    float* tcabs  = p; p += 262144;                  // [4096][64] f32 (invd folded)
    float4* ab4   = (float4*)p; p += 524288;         // [128][1024] float4
    unsigned short* scaled = (unsigned short*)p; p += 4194304;   // [4096][2048] bf16
    unsigned short* zbuf_bf = (unsigned short*)p; p += 1048576;  // [4096][512] bf16
    unsigned short* x_bf    = (unsigned short*)p; p += 1048576;
    unsigned short* h_bf    = (unsigned short*)p; p += 1048576;
    unsigned short* Wtcbf   = (unsigned short*)p; p += 32768;    // [2][64][512] bf16
    unsigned short* W0bf    = (unsigned short*)p; p += 1048576;  // [2][512][2048] bf16
    unsigned short* W1bf    = (unsigned short*)p; p += 262144;   // [2][512][512] bf16

    setup_kernel<<<(NCV + NPK + 255) / 256, 256, 0, stream>>>(
        (const float4*)x, (const float4*)W0, (const float4*)W1, Wt, Wc,
        (ushort4*)x_bf, (ushort4*)W0bf, (ushort4*)W1bf, (ushort4*)Wtcbf);

    for (int i = 0; i < LL; ++i) {
        const unsigned short* hb = (i == 0) ? x_bf : h_bf;
        proj_denom_kernel<<<64, 256, 0, stream>>>(
            hb, Wtcbf + (size_t)i * 64 * 512, tcabs);
        scan_pass1<<<NCHUNK * RC / 256, 256, 0, stream>>>(
            tcabs, start, a + i * RR, b + i * CC, ab4);
        scan_pass2f<<<NCHUNK * 4, 256, 0, stream>>>(
            tcabs, ab4, start, a + i * RR, b + i * CC,
            s0r + i * RC, s0i + i * RC, scaled);
        gemm_ln<2048><<<256, 256, 0, stream>>>(
            scaled, W0bf + (size_t)i * 512 * 2048,
            b0 + i * DD, g0 + i * DD, be0 + i * DD,
            zbuf_bf, nullptr, nullptr, nullptr);
        gemm_ln<512><<<256, 256, 0, stream>>>(
            zbuf_bf, W1bf + (size_t)i * 512 * 512,
            b1 + i * DD, g1 + i * DD, be1 + i * DD,
            nullptr,
            (i < LL - 1) ? x : nullptr,
            (i < LL - 1) ? h_bf : nullptr,
            (i == LL - 1) ? out : nullptr);
    }
}

// Round 11
// 225.695 us; speedup vs baseline: 1.2318x; 1.2318x over previous
//
#include <hip/hip_runtime.h>
#include <math.h>

// Problem constants
#define TT 4096
#define DD 512
#define RR 32
#define CC 32
#define RC 1024
#define LL 2
#define CHUNK 32
#define NCHUNK 128
#define NEG_SLOPE 0.01f
#define LN_EPS 1e-5f

typedef __attribute__((ext_vector_type(8))) __bf16 bf16x8;
typedef __attribute__((ext_vector_type(4))) float f32x4;

__device__ __forceinline__ unsigned short f2bf(float f) {
    unsigned int u = __builtin_bit_cast(unsigned int, f);
    u += 0x7fffu + ((u >> 16) & 1u);   // round-to-nearest-even
    return (unsigned short)(u >> 16);
}

// ---------------------------------------------------------------------------
// Fused setup: f32->bf16 for x, W0, W1, plus Wt/Wc pack into Wtc[L,64,512].
#define NX4  524288   // 4096*512/4
#define NW04 524288   // 2*512*2048/4
#define NW14 131072   // 2*512*512/4
#define NCV  (NX4 + NW04 + NW14)
#define NPK  16384    // 2*64*512/4
__global__ __launch_bounds__(256) void setup_kernel(const float4* __restrict__ x,
                                                    const float4* __restrict__ W0,
                                                    const float4* __restrict__ W1,
                                                    const float* __restrict__ Wt,
                                                    const float* __restrict__ Wc,
                                                    ushort4* __restrict__ xb,
                                                    ushort4* __restrict__ W0b,
                                                    ushort4* __restrict__ W1b,
                                                    ushort4* __restrict__ Wtc) {
    int i = blockIdx.x * 256 + threadIdx.x;
    float4 v;
    ushort4* dst;
    int j;
    if (i < NCV) {
        const float4* src;
        if (i < NX4) { src = x; dst = xb; j = i; }
        else if (i < NX4 + NW04) { src = W0; dst = W0b; j = i - NX4; }
        else { src = W1; dst = W1b; j = i - NX4 - NW04; }
        v = src[j];
    } else {
        int ii = i - NCV;
        if (ii >= NPK) return;
        int e = ii * 4;
        int l = e >> 15;
        int r = (e >> 9) & 63;
        int k = e & 511;
        v = (r < 32) ? *(const float4*)&Wt[((size_t)l * 32 + r) * 512 + k]
                     : *(const float4*)&Wc[((size_t)l * 32 + (r - 32)) * 512 + k];
        dst = Wtc; j = ii;
    }
    ushort4 o;
    o.x = f2bf(v.x); o.y = f2bf(v.y); o.z = f2bf(v.z); o.w = f2bf(v.w);
    dst[j] = o;
}

// ---------------------------------------------------------------------------
// proj + denom + scan-pass1 fused.
// Phase 1 (R7-proven): tc[64 rows] = h @ [Wt;Wc]^T; tcabs with invd folded.
// Phase 2: this block's 64 t-rows = chunks 2*bx, 2*bx+1; compute their
// affine transforms (alpha,beta) reading the tile from LDS. grid 64.
__global__ __launch_bounds__(256) void proj_scan_kernel(const unsigned short* __restrict__ A,
                                                        const unsigned short* __restrict__ B,
                                                        const int* __restrict__ start,
                                                        const float* __restrict__ a,
                                                        const float* __restrict__ b,
                                                        float* __restrict__ tcabs,
                                                        float4* __restrict__ ab4) {
    __shared__ __align__(16) unsigned short As[64 * 32];
    __shared__ __align__(16) unsigned short Bs[64 * 32];
    __shared__ float tct[64][64];
    const int tid = threadIdx.x;
    const int w = tid >> 6, lane = tid & 63;
    const int bm = blockIdx.x * 64;
    const int K = 512;
    const int srow = tid >> 2;           // 0..63
    const int sl = tid & 3;              // 16B slot
    const int sswz = (sl ^ ((srow >> 1) & 3)) * 8;
    const unsigned short* gA = A + (size_t)(bm + srow) * K + sl * 8;
    const unsigned short* gB = B + (size_t)srow * K + sl * 8;
    const int wA = srow * 32 + sswz;
    const int wB = srow * 32 + sswz;
    const int fr = lane & 15, hi = lane >> 4;
    const int kslot = hi ^ ((fr >> 1) & 3);
    f32x4 acc0 = {}, acc1 = {}, acc2 = {}, acc3 = {};

    uint4 va = *(const uint4*)gA;
    uint4 vb = *(const uint4*)gB;
    for (int k0 = 0; k0 < K; k0 += 32) {
        __syncthreads();
        *(uint4*)&As[wA] = va;
        *(uint4*)&Bs[wB] = vb;
        __syncthreads();
        if (k0 + 32 < K) {
            va = *(const uint4*)(gA + k0 + 32);
            vb = *(const uint4*)(gB + k0 + 32);
        }
        const int arow = w * 16 + fr;
        bf16x8 af = *(const bf16x8*)&As[arow * 32 + kslot * 8];
        bf16x8 b0 = *(const bf16x8*)&Bs[(0 * 16 + fr) * 32 + kslot * 8];
        bf16x8 b1 = *(const bf16x8*)&Bs[(1 * 16 + fr) * 32 + kslot * 8];
        bf16x8 b2 = *(const bf16x8*)&Bs[(2 * 16 + fr) * 32 + kslot * 8];
        bf16x8 b3 = *(const bf16x8*)&Bs[(3 * 16 + fr) * 32 + kslot * 8];
        acc0 = __builtin_amdgcn_mfma_f32_16x16x32_bf16(af, b0, acc0, 0, 0, 0);
        acc1 = __builtin_amdgcn_mfma_f32_16x16x32_bf16(af, b1, acc1, 0, 0, 0);
        acc2 = __builtin_amdgcn_mfma_f32_16x16x32_bf16(af, b2, acc2, 0, 0, 0);
        acc3 = __builtin_amdgcn_mfma_f32_16x16x32_bf16(af, b3, acc3, 0, 0, 0);
    }
    // denom epilogue; write tcabs (global) + tct (LDS)
#pragma unroll
    for (int q = 0; q < 4; ++q) {
        float a0 = fabsf(acc0[q]), a1 = fabsf(acc1[q]);
        float a2 = fabsf(acc2[q]), a3 = fabsf(acc3[q]);
        float st = a0 + a1, sc = a2 + a3;
        st += __shfl_xor(st, 1); sc += __shfl_xor(sc, 1);
        st += __shfl_xor(st, 2); sc += __shfl_xor(sc, 2);
        st += __shfl_xor(st, 4); sc += __shfl_xor(sc, 4);
        st += __shfl_xor(st, 8); sc += __shfl_xor(sc, 8);
        float inv = 1.f / (1e-8f + st * sc);
        int lrow = w * 16 + hi * 4 + q;
        size_t rb = (size_t)(bm + lrow) * 64;
        float v0 = a0 * inv, v1 = a1 * inv;
        tcabs[rb + fr]      = v0;
        tcabs[rb + fr + 16] = v1;
        tcabs[rb + fr + 32] = a2;
        tcabs[rb + fr + 48] = a3;
        tct[lrow][fr]      = v0;
        tct[lrow][fr + 16] = v1;
        tct[lrow][fr + 32] = a2;
        tct[lrow][fr + 48] = a3;
    }
    __syncthreads();
    // scan pass 1 for chunks 2*bx and 2*bx+1 (t-local rows 0..31, 32..63)
#pragma unroll
    for (int u = 0; u < 8; ++u) {
        int item = u * 256 + tid;        // 0..2047
        int cl = item >> 10;             // local chunk 0/1
        int rc = item & 1023;
        int r = rc >> 5, c = rc & 31;
        float e = expf(-fabsf(a[r]));
        float gr = e * cosf(b[c]);
        float gi = e * sinf(b[c]);
        float alr = 1.f, ali = 0.f, ber = 0.f, bei = 0.f;
        int t0 = cl * 32;
        for (int j = 0; j < 32; ++j) {
            int tl = t0 + j;
            float pre = tct[tl][r] * tct[tl][32 + c];
            if (start[bm + tl]) {
                alr = 0.f; ali = 0.f; ber = pre; bei = 0.f;
            } else {
                float nbr = pre + gr * ber - gi * bei;
                float nbi =       gr * bei + gi * ber;
                float nar = gr * alr - gi * ali;
                float nai = gr * ali + gi * alr;
                ber = nbr; bei = nbi; alr = nar; ali = nai;
            }
        }
        ab4[(size_t)(blockIdx.x * 2 + cl) * RC + rc] = make_float4(alr, ali, ber, bei);
    }
}

// ---------------------------------------------------------------------------
// Scan pass 2 + in-block lookback: compose ab4[0..chunk-1] (8-deep prefetch),
// then rescan own chunk, emit scaled features (bf16).
// grid 512: chunk = bx>>2, rc = (bx&3)*256 + tx.
__global__ __launch_bounds__(256) void scan_pass2f(const float* __restrict__ tcabs,
                                                   const float4* __restrict__ ab4,
                                                   const int* __restrict__ start,
                                                   const float* __restrict__ a,
                                                   const float* __restrict__ b,
                                                   const float* __restrict__ s0r,
                                                   const float* __restrict__ s0i,
                                                   unsigned short* __restrict__ scaled) {
    int bx = blockIdx.x;
    int chunk = bx >> 2;
    int rc = (bx & 3) * 256 + threadIdx.x;
    int r = rc >> 5, c = rc & 31;
    float e = expf(-fabsf(a[r]));
    float gr = e * cosf(b[c]);
    float gi = e * sinf(b[c]);
    float sr = s0r[rc], si = s0i[rc];
    int j = 0;
    for (; j + 8 <= chunk; j += 8) {
        float4 buf[8];
#pragma unroll
        for (int u = 0; u < 8; ++u) buf[u] = ab4[(j + u) * RC + rc];
#pragma unroll
        for (int u = 0; u < 8; ++u) {
            float nsr = buf[u].z + buf[u].x * sr - buf[u].y * si;
            float nsi = buf[u].w + buf[u].x * si + buf[u].y * sr;
            sr = nsr; si = nsi;
        }
    }
    for (; j < chunk; ++j) {
        float4 ab = ab4[j * RC + rc];
        float nsr = ab.z + ab.x * sr - ab.y * si;
        float nsi = ab.w + ab.x * si + ab.y * sr;
        sr = nsr; si = nsi;
    }
    int t0 = chunk * CHUNK;
    for (int jj = 0; jj < CHUNK; ++jj) {
        int t = t0 + jj;
        float pre = tcabs[t * 64 + r] * tcabs[t * 64 + 32 + c];
        if (start[t]) {
            sr = pre; si = 0.f;
        } else {
            float nsr = pre + gr * sr - gi * si;
            float nsi =       gr * si + gi * sr;
            sr = nsr; si = nsi;
        }
        float m = sqrtf(sr * sr + si * si);
        float mag = log1pf(m);
        float f = (m > 0.f) ? (mag / m) : 0.f;
        scaled[(size_t)t * 2048 + rc]        = f2bf(si * f);
        scaled[(size_t)t * 2048 + 1024 + rc] = f2bf(sr * f);
    }
}

// ---------------------------------------------------------------------------
// Cm_partial[z][4096,N] = A[4096,Kz]bf16 @ B[N,Kz]bf16^T  (split-K partials)
// Tile 128x64, BK=32, 4 waves, named-scalar staging (R7 champion version).
// XCD-chunked logical-block swizzle (bijective since nwg % 8 == 0).
template <int K, int N, int SPLITK>
__global__ __launch_bounds__(256) void gemm_bt_mfma(const unsigned short* __restrict__ A,
                                                    const unsigned short* __restrict__ B,
                                                    float* __restrict__ Cm) {
    __shared__ __align__(16) unsigned short As[128 * 32];
    __shared__ __align__(16) unsigned short Bs[64 * 32];
    const int tid = threadIdx.x;
    const int w = tid >> 6, lane = tid & 63;
    const int nwg = gridDim.x * gridDim.y * gridDim.z;
    const int id = blockIdx.x + gridDim.x * (blockIdx.y + gridDim.y * blockIdx.z);
    const int lid = (id & 7) * (nwg >> 3) + (id >> 3);
    const int bxs = lid % gridDim.x;
    const int t2 = lid / gridDim.x;
    const int bys = t2 % gridDim.y;
    const int bzs = t2 / gridDim.y;
    const int bm = bys * 128, bn = bxs * 64;
    const int kbeg = bzs * (K / SPLITK);
    const int kend = kbeg + (K / SPLITK);
    const int wr = w >> 1, wc = w & 1;
    const int lr = lane >> 2;
    const int sl = lane & 3;
    const int swz_st = sl ^ ((lr >> 1) & 3);
    const size_t a_row0 = (size_t)(bm + w * 16 + lr);
    const size_t a_row1 = (size_t)(bm + 64 + w * 16 + lr);
    const size_t b_row  = (size_t)(bn + w * 16 + lr);
    const unsigned short* gA0 = A + a_row0 * K + sl * 8;
    const unsigned short* gA1 = A + a_row1 * K + sl * 8;
    const unsigned short* gB  = B + b_row  * K + sl * 8;
    const int wA0 = (w * 16 + lr) * 32 + swz_st * 8;
    const int wA1 = (64 + w * 16 + lr) * 32 + swz_st * 8;
    const int wB  = (w * 16 + lr) * 32 + swz_st * 8;
    const int fr = lane & 15, hi = lane >> 4;
    const int kslot = hi ^ ((fr >> 1) & 3);
    f32x4 acc[4][2] = {};

    uint4 va0 = *(const uint4*)(gA0 + kbeg);
    uint4 va1 = *(const uint4*)(gA1 + kbeg);
    uint4 vb  = *(const uint4*)(gB  + kbeg);
    for (int k0 = kbeg; k0 < kend; k0 += 32) {
        __syncthreads();
        *(uint4*)&As[wA0] = va0;
        *(uint4*)&As[wA1] = va1;
        *(uint4*)&Bs[wB]  = vb;
        __syncthreads();
        if (k0 + 32 < kend) {
            va0 = *(const uint4*)(gA0 + k0 + 32);
            va1 = *(const uint4*)(gA1 + k0 + 32);
            vb  = *(const uint4*)(gB  + k0 + 32);
        }
        bf16x8 af[4], bfv[2];
#pragma unroll
        for (int mi = 0; mi < 4; ++mi) {
            int row = wr * 64 + mi * 16 + fr;
            af[mi] = *(const bf16x8*)&As[row * 32 + kslot * 8];
        }
#pragma unroll
        for (int ni = 0; ni < 2; ++ni) {
            int row = wc * 32 + ni * 16 + fr;
            bfv[ni] = *(const bf16x8*)&Bs[row * 32 + kslot * 8];
        }
#pragma unroll
        for (int mi = 0; mi < 4; ++mi)
#pragma unroll
            for (int ni = 0; ni < 2; ++ni)
                acc[mi][ni] = __builtin_amdgcn_mfma_f32_16x16x32_bf16(
                    af[mi], bfv[ni], acc[mi][ni], 0, 0, 0);
    }
    // epilogue: C/D layout col=lane&15, row=(lane>>4)*4+reg  [m89]
    float* Cz = Cm + (size_t)bzs * TT * N;
    const int ccol0 = bn + wc * 32 + fr;
    const int crow0 = bm + wr * 64 + hi * 4;
#pragma unroll
    for (int ni = 0; ni < 2; ++ni) {
        int col = ccol0 + ni * 16;
#pragma unroll
        for (int mi = 0; mi < 4; ++mi)
#pragma unroll
            for (int q = 0; q < 4; ++q)
                Cz[(size_t)(crow0 + mi * 16 + q) * N + col] = acc[mi][ni][q];
    }
}

// ---------------------------------------------------------------------------
// Per-row: y = y0 + y1 + bias; LayerNorm + LeakyReLU.
__global__ __launch_bounds__(256) void ln_lrelu_kernel(const float* __restrict__ y0,
                                                       const float* __restrict__ y1,
                                                       const float* __restrict__ badd,
                                                       const float* __restrict__ g,
                                                       const float* __restrict__ be,
                                                       unsigned short* __restrict__ zb,
                                                       const float* __restrict__ res,
                                                       unsigned short* __restrict__ hbf,
                                                       float* __restrict__ fout) {
    int t = blockIdx.x;
    int tid = threadIdx.x;
    size_t base = (size_t)t * 512;
    float v0 = y0[base + tid] + y1[base + tid] + badd[tid];
    float v1 = y0[base + 256 + tid] + y1[base + 256 + tid] + badd[256 + tid];
    float s = v0 + v1, ss = v0 * v0 + v1 * v1;
#pragma unroll
    for (int o = 32; o > 0; o >>= 1) {
        s  += __shfl_down(s, o);
        ss += __shfl_down(ss, o);
    }
    __shared__ float sh[8];
    __shared__ float mrs[2];
    int wid = tid >> 6, lane = tid & 63;
    if (lane == 0) { sh[wid] = s; sh[4 + wid] = ss; }
    __syncthreads();
    if (tid == 0) {
        float S = sh[0] + sh[1] + sh[2] + sh[3];
        float SS = sh[4] + sh[5] + sh[6] + sh[7];
        float m = S * (1.f / 512.f);
        float var = SS * (1.f / 512.f) - m * m;
        mrs[0] = m;
        mrs[1] = rsqrtf(var + LN_EPS);
    }
    __syncthreads();
    float m = mrs[0], rs = mrs[1];
    float z0 = g[tid] * (v0 - m) * rs + be[tid];
    float z1 = g[256 + tid] * (v1 - m) * rs + be[256 + tid];
    z0 = (z0 > 0.f) ? z0 : NEG_SLOPE * z0;
    z1 = (z1 > 0.f) ? z1 : NEG_SLOPE * z1;
    if (zb)   { zb[base + tid] = f2bf(z0); zb[base + 256 + tid] = f2bf(z1); }
    if (hbf) {
        float h0 = (res ? res[base + tid] : 0.f) + z0;
        float h1 = (res ? res[base + 256 + tid] : 0.f) + z1;
        hbf[base + tid] = f2bf(h0);
        hbf[base + 256 + tid] = f2bf(h1);
    }
    if (fout) { fout[base + tid] = z0; fout[base + 256 + tid] = z1; }
}

// ---------------------------------------------------------------------------
extern "C" void kernel_launch(void* const* d_in, const int* in_sizes, int n_in,
                              void* d_out, int out_size, void* d_ws, size_t ws_size,
                              hipStream_t stream) {
    const float* x     = (const float*)d_in[0];
    const int*   start = (const int*)d_in[1];
    const float* s0r = (const float*)d_in[3];
    const float* s0i = (const float*)d_in[4];
    const float* Wt  = (const float*)d_in[5];
    const float* Wc  = (const float*)d_in[6];
    const float* a   = (const float*)d_in[7];
    const float* b   = (const float*)d_in[8];
    const float* W0  = (const float*)d_in[9];
    const float* b0  = (const float*)d_in[10];
    const float* g0  = (const float*)d_in[11];
    const float* be0 = (const float*)d_in[12];
    const float* W1  = (const float*)d_in[13];
    const float* b1  = (const float*)d_in[14];
    const float* g1  = (const float*)d_in[15];
    const float* be1 = (const float*)d_in[16];
    float* out = (float*)d_out;
    float* ws  = (float*)d_ws;

    // workspace layout (float-unit offsets, all 16B aligned)  ~50 MB
    float* p = ws;
    float* tcabs  = p; p += 262144;                  // [4096][64] f32 (invd folded)
    float4* ab4   = (float4*)p; p += 524288;         // [128][1024] float4
    unsigned short* scaled = (unsigned short*)p; p += 4194304;   // [4096][2048] bf16
    float* ybufp  = p; p += 4194304;                 // [2][4096][512] f32 partials
    unsigned short* zbuf_bf = (unsigned short*)p; p += 1048576;  // [4096][512] bf16
    unsigned short* x_bf    = (unsigned short*)p; p += 1048576;
    unsigned short* h_bf    = (unsigned short*)p; p += 1048576;
    unsigned short* Wtcbf   = (unsigned short*)p; p += 32768;    // [2][64][512] bf16
    unsigned short* W0bf    = (unsigned short*)p; p += 1048576;  // [2][512][2048] bf16
    unsigned short* W1bf    = (unsigned short*)p; p += 262144;   // [2][512][512] bf16

    setup_kernel<<<(NCV + NPK + 255) / 256, 256, 0, stream>>>(
        (const float4*)x, (const float4*)W0, (const float4*)W1, Wt, Wc,
        (ushort4*)x_bf, (ushort4*)W0bf, (ushort4*)W1bf, (ushort4*)Wtcbf);

    for (int i = 0; i < LL; ++i) {
        const unsigned short* hb = (i == 0) ? x_bf : h_bf;
        proj_scan_kernel<<<64, 256, 0, stream>>>(
            hb, Wtcbf + (size_t)i * 64 * 512, start, a + i * RR, b + i * CC,
            tcabs, ab4);
        scan_pass2f<<<NCHUNK * 4, 256, 0, stream>>>(
            tcabs, ab4, start, a + i * RR, b + i * CC,
            s0r + i * RC, s0i + i * RC, scaled);
        gemm_bt_mfma<2048, 512, 2><<<dim3(8, 32, 2), 256, 0, stream>>>(
            scaled, W0bf + (size_t)i * 512 * 2048, ybufp);
        ln_lrelu_kernel<<<TT, 256, 0, stream>>>(
            ybufp, ybufp + (size_t)TT * 512, b0 + i * DD, g0 + i * DD, be0 + i * DD,
            zbuf_bf, nullptr, nullptr, nullptr);
        gemm_bt_mfma<512, 512, 2><<<dim3(8, 32, 2), 256, 0, stream>>>(
            zbuf_bf, W1bf + (size_t)i * 512 * 512, ybufp);
        ln_lrelu_kernel<<<TT, 256, 0, stream>>>(
            ybufp, ybufp + (size_t)TT * 512, b1 + i * DD, g1 + i * DD, be1 + i * DD,
            nullptr,
            (i < LL - 1) ? x : nullptr,
            (i < LL - 1) ? h_bf : nullptr,
            (i == LL - 1) ? out : nullptr);
    }
}

// Round 12
// 196.000 us; speedup vs baseline: 1.4184x; 1.1515x over previous
//
#include <hip/hip_runtime.h>
#include <math.h>

// Problem constants
#define TT 4096
#define DD 512
#define RR 32
#define CC 32
#define RC 1024
#define LL 2
#define CHUNK 32
#define NCHUNK 128
#define NEG_SLOPE 0.01f
#define LN_EPS 1e-5f

typedef __attribute__((ext_vector_type(8))) __bf16 bf16x8;
typedef __attribute__((ext_vector_type(4))) float f32x4;

__device__ __forceinline__ unsigned short f2bf(float f) {
    unsigned int u = __builtin_bit_cast(unsigned int, f);
    u += 0x7fffu + ((u >> 16) & 1u);   // round-to-nearest-even
    return (unsigned short)(u >> 16);
}

// ---------------------------------------------------------------------------
// Fused setup: f32->bf16 for x, W0, W1, plus Wt/Wc pack into Wtc[L,64,512].
#define NX4  524288   // 4096*512/4
#define NW04 524288   // 2*512*2048/4
#define NW14 131072   // 2*512*512/4
#define NCV  (NX4 + NW04 + NW14)
#define NPK  16384    // 2*64*512/4
__global__ __launch_bounds__(256) void setup_kernel(const float4* __restrict__ x,
                                                    const float4* __restrict__ W0,
                                                    const float4* __restrict__ W1,
                                                    const float* __restrict__ Wt,
                                                    const float* __restrict__ Wc,
                                                    ushort4* __restrict__ xb,
                                                    ushort4* __restrict__ W0b,
                                                    ushort4* __restrict__ W1b,
                                                    ushort4* __restrict__ Wtc) {
    int i = blockIdx.x * 256 + threadIdx.x;
    float4 v;
    ushort4* dst;
    int j;
    if (i < NCV) {
        const float4* src;
        if (i < NX4) { src = x; dst = xb; j = i; }
        else if (i < NX4 + NW04) { src = W0; dst = W0b; j = i - NX4; }
        else { src = W1; dst = W1b; j = i - NX4 - NW04; }
        v = src[j];
    } else {
        int ii = i - NCV;
        if (ii >= NPK) return;
        int e = ii * 4;
        int l = e >> 15;
        int r = (e >> 9) & 63;
        int k = e & 511;
        v = (r < 32) ? *(const float4*)&Wt[((size_t)l * 32 + r) * 512 + k]
                     : *(const float4*)&Wc[((size_t)l * 32 + (r - 32)) * 512 + k];
        dst = Wtc; j = ii;
    }
    ushort4 o;
    o.x = f2bf(v.x); o.y = f2bf(v.y); o.z = f2bf(v.z); o.w = f2bf(v.w);
    dst[j] = o;
}

// ---------------------------------------------------------------------------
// proj + denom fused (R7 proven): tcabs[t,r]=|tr_r|*invd (r<32); tcabs[t,32+c]=|ct_c|
__global__ __launch_bounds__(256) void proj_denom_kernel(const unsigned short* __restrict__ A,
                                                         const unsigned short* __restrict__ B,
                                                         float* __restrict__ tcabs) {
    __shared__ __align__(16) unsigned short As[64 * 32];
    __shared__ __align__(16) unsigned short Bs[64 * 32];
    const int tid = threadIdx.x;
    const int w = tid >> 6, lane = tid & 63;
    const int bm = blockIdx.x * 64;
    const int K = 512;
    const int srow = tid >> 2;           // 0..63
    const int sl = tid & 3;              // 16B slot
    const int sswz = (sl ^ ((srow >> 1) & 3)) * 8;
    const unsigned short* gA = A + (size_t)(bm + srow) * K + sl * 8;
    const unsigned short* gB = B + (size_t)srow * K + sl * 8;
    const int wA = srow * 32 + sswz;
    const int wB = srow * 32 + sswz;
    const int fr = lane & 15, hi = lane >> 4;
    const int kslot = hi ^ ((fr >> 1) & 3);
    f32x4 acc0 = {}, acc1 = {}, acc2 = {}, acc3 = {};

    uint4 va = *(const uint4*)gA;
    uint4 vb = *(const uint4*)gB;
    for (int k0 = 0; k0 < K; k0 += 32) {
        __syncthreads();
        *(uint4*)&As[wA] = va;
        *(uint4*)&Bs[wB] = vb;
        __syncthreads();
        if (k0 + 32 < K) {
            va = *(const uint4*)(gA + k0 + 32);
            vb = *(const uint4*)(gB + k0 + 32);
        }
        const int arow = w * 16 + fr;
        bf16x8 af = *(const bf16x8*)&As[arow * 32 + kslot * 8];
        bf16x8 b0 = *(const bf16x8*)&Bs[(0 * 16 + fr) * 32 + kslot * 8];
        bf16x8 b1 = *(const bf16x8*)&Bs[(1 * 16 + fr) * 32 + kslot * 8];
        bf16x8 b2 = *(const bf16x8*)&Bs[(2 * 16 + fr) * 32 + kslot * 8];
        bf16x8 b3 = *(const bf16x8*)&Bs[(3 * 16 + fr) * 32 + kslot * 8];
        acc0 = __builtin_amdgcn_mfma_f32_16x16x32_bf16(af, b0, acc0, 0, 0, 0);
        acc1 = __builtin_amdgcn_mfma_f32_16x16x32_bf16(af, b1, acc1, 0, 0, 0);
        acc2 = __builtin_amdgcn_mfma_f32_16x16x32_bf16(af, b2, acc2, 0, 0, 0);
        acc3 = __builtin_amdgcn_mfma_f32_16x16x32_bf16(af, b3, acc3, 0, 0, 0);
    }
#pragma unroll
    for (int q = 0; q < 4; ++q) {
        float a0 = fabsf(acc0[q]), a1 = fabsf(acc1[q]);
        float a2 = fabsf(acc2[q]), a3 = fabsf(acc3[q]);
        float st = a0 + a1, sc = a2 + a3;
        st += __shfl_xor(st, 1); sc += __shfl_xor(sc, 1);
        st += __shfl_xor(st, 2); sc += __shfl_xor(sc, 2);
        st += __shfl_xor(st, 4); sc += __shfl_xor(sc, 4);
        st += __shfl_xor(st, 8); sc += __shfl_xor(sc, 8);
        float inv = 1.f / (1e-8f + st * sc);
        size_t rb = (size_t)(bm + w * 16 + hi * 4 + q) * 64;
        tcabs[rb + fr]      = a0 * inv;
        tcabs[rb + fr + 16] = a1 * inv;
        tcabs[rb + fr + 32] = a2;
        tcabs[rb + fr + 48] = a3;
    }
}

// ---------------------------------------------------------------------------
// Scan pass 1: per (chunk, r, c) affine transform (alpha, beta) with resets.
__global__ __launch_bounds__(256) void scan_pass1(const float* __restrict__ tcabs,
                                                  const int* __restrict__ start,
                                                  const float* __restrict__ a,
                                                  const float* __restrict__ b,
                                                  float4* __restrict__ ab4) {
    int tid = blockIdx.x * 256 + threadIdx.x;   // NCHUNK*RC = 131072
    int rc = tid & (RC - 1);
    int chunk = tid >> 10;
    int r = rc >> 5, c = rc & 31;
    float e = expf(-fabsf(a[r]));
    float gr = e * cosf(b[c]);
    float gi = e * sinf(b[c]);
    float alr = 1.f, ali = 0.f, ber = 0.f, bei = 0.f;
    int t0 = chunk * CHUNK;
    for (int j = 0; j < CHUNK; ++j) {
        int t = t0 + j;
        float pre = tcabs[t * 64 + r] * tcabs[t * 64 + 32 + c];
        if (start[t]) {
            alr = 0.f; ali = 0.f; ber = pre; bei = 0.f;
        } else {
            float nbr = pre + gr * ber - gi * bei;
            float nbi =       gr * bei + gi * ber;
            float nar = gr * alr - gi * ali;
            float nai = gr * ali + gi * alr;
            ber = nbr; bei = nbi; alr = nar; ali = nai;
        }
    }
    ab4[chunk * RC + rc] = make_float4(alr, ali, ber, bei);
}

// ---------------------------------------------------------------------------
// Scan pass 2 + in-block lookback: compose ab4[0..chunk-1] (8-deep prefetch),
// then rescan own chunk, emit scaled features (bf16).
// grid 512: chunk = bx>>2, rc = (bx&3)*256 + tx.
__global__ __launch_bounds__(256) void scan_pass2f(const float* __restrict__ tcabs,
                                                   const float4* __restrict__ ab4,
                                                   const int* __restrict__ start,
                                                   const float* __restrict__ a,
                                                   const float* __restrict__ b,
                                                   const float* __restrict__ s0r,
                                                   const float* __restrict__ s0i,
                                                   unsigned short* __restrict__ scaled) {
    int bx = blockIdx.x;
    int chunk = bx >> 2;
    int rc = (bx & 3) * 256 + threadIdx.x;
    int r = rc >> 5, c = rc & 31;
    float e = expf(-fabsf(a[r]));
    float gr = e * cosf(b[c]);
    float gi = e * sinf(b[c]);
    float sr = s0r[rc], si = s0i[rc];
    int j = 0;
    for (; j + 8 <= chunk; j += 8) {
        float4 buf[8];
#pragma unroll
        for (int u = 0; u < 8; ++u) buf[u] = ab4[(j + u) * RC + rc];
#pragma unroll
        for (int u = 0; u < 8; ++u) {
            float nsr = buf[u].z + buf[u].x * sr - buf[u].y * si;
            float nsi = buf[u].w + buf[u].x * si + buf[u].y * sr;
            sr = nsr; si = nsi;
        }
    }
    for (; j < chunk; ++j) {
        float4 ab = ab4[j * RC + rc];
        float nsr = ab.z + ab.x * sr - ab.y * si;
        float nsi = ab.w + ab.x * si + ab.y * sr;
        sr = nsr; si = nsi;
    }
    int t0 = chunk * CHUNK;
    for (int jj = 0; jj < CHUNK; ++jj) {
        int t = t0 + jj;
        float pre = tcabs[t * 64 + r] * tcabs[t * 64 + 32 + c];
        if (start[t]) {
            sr = pre; si = 0.f;
        } else {
            float nsr = pre + gr * sr - gi * si;
            float nsi =       gr * si + gi * sr;
            sr = nsr; si = nsi;
        }
        float m = sqrtf(sr * sr + si * si);
        float mag = log1pf(m);
        float f = (m > 0.f) ? (mag / m) : 0.f;
        scaled[(size_t)t * 2048 + rc]        = f2bf(si * f);
        scaled[(size_t)t * 2048 + 1024 + rc] = f2bf(sr * f);
    }
}

// ---------------------------------------------------------------------------
// Cm_partial[z][4096,N] = A[4096,Kz]bf16 @ B[N,Kz]bf16^T  (split-K partials)
// Tile 128x64, BK=32, 4 waves, named-scalar staging (R7 champion version).
// XCD-chunked logical-block swizzle (bijective since nwg % 8 == 0).
template <int K, int N, int SPLITK>
__global__ __launch_bounds__(256) void gemm_bt_mfma(const unsigned short* __restrict__ A,
                                                    const unsigned short* __restrict__ B,
                                                    float* __restrict__ Cm) {
    __shared__ __align__(16) unsigned short As[128 * 32];
    __shared__ __align__(16) unsigned short Bs[64 * 32];
    const int tid = threadIdx.x;
    const int w = tid >> 6, lane = tid & 63;
    const int nwg = gridDim.x * gridDim.y * gridDim.z;
    const int id = blockIdx.x + gridDim.x * (blockIdx.y + gridDim.y * blockIdx.z);
    const int lid = (id & 7) * (nwg >> 3) + (id >> 3);
    const int bxs = lid % gridDim.x;
    const int t2 = lid / gridDim.x;
    const int bys = t2 % gridDim.y;
    const int bzs = t2 / gridDim.y;
    const int bm = bys * 128, bn = bxs * 64;
    const int kbeg = bzs * (K / SPLITK);
    const int kend = kbeg + (K / SPLITK);
    const int wr = w >> 1, wc = w & 1;
    const int lr = lane >> 2;
    const int sl = lane & 3;
    const int swz_st = sl ^ ((lr >> 1) & 3);
    const size_t a_row0 = (size_t)(bm + w * 16 + lr);
    const size_t a_row1 = (size_t)(bm + 64 + w * 16 + lr);
    const size_t b_row  = (size_t)(bn + w * 16 + lr);
    const unsigned short* gA0 = A + a_row0 * K + sl * 8;
    const unsigned short* gA1 = A + a_row1 * K + sl * 8;
    const unsigned short* gB  = B + b_row  * K + sl * 8;
    const int wA0 = (w * 16 + lr) * 32 + swz_st * 8;
    const int wA1 = (64 + w * 16 + lr) * 32 + swz_st * 8;
    const int wB  = (w * 16 + lr) * 32 + swz_st * 8;
    const int fr = lane & 15, hi = lane >> 4;
    const int kslot = hi ^ ((fr >> 1) & 3);
    f32x4 acc[4][2] = {};

    uint4 va0 = *(const uint4*)(gA0 + kbeg);
    uint4 va1 = *(const uint4*)(gA1 + kbeg);
    uint4 vb  = *(const uint4*)(gB  + kbeg);
    for (int k0 = kbeg; k0 < kend; k0 += 32) {
        __syncthreads();
        *(uint4*)&As[wA0] = va0;
        *(uint4*)&As[wA1] = va1;
        *(uint4*)&Bs[wB]  = vb;
        __syncthreads();
        if (k0 + 32 < kend) {
            va0 = *(const uint4*)(gA0 + k0 + 32);
            va1 = *(const uint4*)(gA1 + k0 + 32);
            vb  = *(const uint4*)(gB  + k0 + 32);
        }
        bf16x8 af[4], bfv[2];
#pragma unroll
        for (int mi = 0; mi < 4; ++mi) {
            int row = wr * 64 + mi * 16 + fr;
            af[mi] = *(const bf16x8*)&As[row * 32 + kslot * 8];
        }
#pragma unroll
        for (int ni = 0; ni < 2; ++ni) {
            int row = wc * 32 + ni * 16 + fr;
            bfv[ni] = *(const bf16x8*)&Bs[row * 32 + kslot * 8];
        }
#pragma unroll
        for (int mi = 0; mi < 4; ++mi)
#pragma unroll
            for (int ni = 0; ni < 2; ++ni)
                acc[mi][ni] = __builtin_amdgcn_mfma_f32_16x16x32_bf16(
                    af[mi], bfv[ni], acc[mi][ni], 0, 0, 0);
    }
    // epilogue: C/D layout col=lane&15, row=(lane>>4)*4+reg  [m89]
    float* Cz = Cm + (size_t)bzs * TT * N;
    const int ccol0 = bn + wc * 32 + fr;
    const int crow0 = bm + wr * 64 + hi * 4;
#pragma unroll
    for (int ni = 0; ni < 2; ++ni) {
        int col = ccol0 + ni * 16;
#pragma unroll
        for (int mi = 0; mi < 4; ++mi)
#pragma unroll
            for (int q = 0; q < 4; ++q)
                Cz[(size_t)(crow0 + mi * 16 + q) * N + col] = acc[mi][ni][q];
    }
}

// ---------------------------------------------------------------------------
// Wave-per-row LayerNorm + LeakyReLU: y = y0 + y1 + bias, LN over 512 cols.
// grid 1024 x 256 thr; wave handles one row, lane covers 8 cols (2x float4
// per partial = 16B/lane loads). In-wave shfl_xor reduce; no LDS, no barrier.
__global__ __launch_bounds__(256) void ln_lrelu_kernel(const float* __restrict__ y0,
                                                       const float* __restrict__ y1,
                                                       const float* __restrict__ badd,
                                                       const float* __restrict__ g,
                                                       const float* __restrict__ be,
                                                       unsigned short* __restrict__ zb,
                                                       const float* __restrict__ res,
                                                       unsigned short* __restrict__ hbf,
                                                       float* __restrict__ fout) {
    const int lane = threadIdx.x & 63;
    const int row = blockIdx.x * 4 + (threadIdx.x >> 6);
    const size_t base = (size_t)row * 512 + lane * 8;
    const int cb = lane * 8;
    float4 p0a = *(const float4*)&y0[base];
    float4 p0b = *(const float4*)&y0[base + 4];
    float4 p1a = *(const float4*)&y1[base];
    float4 p1b = *(const float4*)&y1[base + 4];
    float4 ba = *(const float4*)&badd[cb];
    float4 bb = *(const float4*)&badd[cb + 4];
    float v[8];
    v[0] = p0a.x + p1a.x + ba.x; v[1] = p0a.y + p1a.y + ba.y;
    v[2] = p0a.z + p1a.z + ba.z; v[3] = p0a.w + p1a.w + ba.w;
    v[4] = p0b.x + p1b.x + bb.x; v[5] = p0b.y + p1b.y + bb.y;
    v[6] = p0b.z + p1b.z + bb.z; v[7] = p0b.w + p1b.w + bb.w;
    float s = 0.f, ss = 0.f;
#pragma unroll
    for (int j = 0; j < 8; ++j) { s += v[j]; ss += v[j] * v[j]; }
#pragma unroll
    for (int o = 1; o < 64; o <<= 1) {
        s  += __shfl_xor(s, o);
        ss += __shfl_xor(ss, o);
    }
    float m = s * (1.f / 512.f);
    float rs = rsqrtf(ss * (1.f / 512.f) - m * m + LN_EPS);
    float4 ga = *(const float4*)&g[cb];
    float4 gb = *(const float4*)&g[cb + 4];
    float4 ea = *(const float4*)&be[cb];
    float4 eb = *(const float4*)&be[cb + 4];
    float gg[8] = {ga.x, ga.y, ga.z, ga.w, gb.x, gb.y, gb.z, gb.w};
    float ee[8] = {ea.x, ea.y, ea.z, ea.w, eb.x, eb.y, eb.z, eb.w};
    float z[8];
#pragma unroll
    for (int j = 0; j < 8; ++j) {
        float zz = gg[j] * (v[j] - m) * rs + ee[j];
        z[j] = (zz > 0.f) ? zz : NEG_SLOPE * zz;
    }
    if (zb) {
        ushort4 o0, o1;
        o0.x = f2bf(z[0]); o0.y = f2bf(z[1]); o0.z = f2bf(z[2]); o0.w = f2bf(z[3]);
        o1.x = f2bf(z[4]); o1.y = f2bf(z[5]); o1.z = f2bf(z[6]); o1.w = f2bf(z[7]);
        *(ushort4*)&zb[base] = o0;
        *(ushort4*)&zb[base + 4] = o1;
    }
    if (hbf) {
        float4 ra = *(const float4*)&res[base];
        float4 rb2 = *(const float4*)&res[base + 4];
        ushort4 o0, o1;
        o0.x = f2bf(ra.x + z[0]); o0.y = f2bf(ra.y + z[1]);
        o0.z = f2bf(ra.z + z[2]); o0.w = f2bf(ra.w + z[3]);
        o1.x = f2bf(rb2.x + z[4]); o1.y = f2bf(rb2.y + z[5]);
        o1.z = f2bf(rb2.z + z[6]); o1.w = f2bf(rb2.w + z[7]);
        *(ushort4*)&hbf[base] = o0;
        *(ushort4*)&hbf[base + 4] = o1;
    }
    if (fout) {
        *(float4*)&fout[base] = make_float4(z[0], z[1], z[2], z[3]);
        *(float4*)&fout[base + 4] = make_float4(z[4], z[5], z[6], z[7]);
    }
}

// ---------------------------------------------------------------------------
extern "C" void kernel_launch(void* const* d_in, const int* in_sizes, int n_in,
                              void* d_out, int out_size, void* d_ws, size_t ws_size,
                              hipStream_t stream) {
    const float* x     = (const float*)d_in[0];
    const int*   start = (const int*)d_in[1];
    const float* s0r = (const float*)d_in[3];
    const float* s0i = (const float*)d_in[4];
    const float* Wt  = (const float*)d_in[5];
    const float* Wc  = (const float*)d_in[6];
    const float* a   = (const float*)d_in[7];
    const float* b   = (const float*)d_in[8];
    const float* W0  = (const float*)d_in[9];
    const float* b0  = (const float*)d_in[10];
    const float* g0  = (const float*)d_in[11];
    const float* be0 = (const float*)d_in[12];
    const float* W1  = (const float*)d_in[13];
    const float* b1  = (const float*)d_in[14];
    const float* g1  = (const float*)d_in[15];
    const float* be1 = (const float*)d_in[16];
    float* out = (float*)d_out;
    float* ws  = (float*)d_ws;

    // workspace layout (float-unit offsets, all 16B aligned)  ~50 MB
    float* p = ws;
    float* tcabs  = p; p += 262144;                  // [4096][64] f32 (invd folded)
    float4* ab4   = (float4*)p; p += 524288;         // [128][1024] float4
    unsigned short* scaled = (unsigned short*)p; p += 4194304;   // [4096][2048] bf16
    float* ybufp  = p; p += 4194304;                 // [2][4096][512] f32 partials
    unsigned short* zbuf_bf = (unsigned short*)p; p += 1048576;  // [4096][512] bf16
    unsigned short* x_bf    = (unsigned short*)p; p += 1048576;
    unsigned short* h_bf    = (unsigned short*)p; p += 1048576;
    unsigned short* Wtcbf   = (unsigned short*)p; p += 32768;    // [2][64][512] bf16
    unsigned short* W0bf    = (unsigned short*)p; p += 1048576;  // [2][512][2048] bf16
    unsigned short* W1bf    = (unsigned short*)p; p += 262144;   // [2][512][512] bf16

    setup_kernel<<<(NCV + NPK + 255) / 256, 256, 0, stream>>>(
        (const float4*)x, (const float4*)W0, (const float4*)W1, Wt, Wc,
        (ushort4*)x_bf, (ushort4*)W0bf, (ushort4*)W1bf, (ushort4*)Wtcbf);

    for (int i = 0; i < LL; ++i) {
        const unsigned short* hb = (i == 0) ? x_bf : h_bf;
        proj_denom_kernel<<<64, 256, 0, stream>>>(
            hb, Wtcbf + (size_t)i * 64 * 512, tcabs);
        scan_pass1<<<NCHUNK * RC / 256, 256, 0, stream>>>(
            tcabs, start, a + i * RR, b + i * CC, ab4);
        scan_pass2f<<<NCHUNK * 4, 256, 0, stream>>>(
            tcabs, ab4, start, a + i * RR, b + i * CC,
            s0r + i * RC, s0i + i * RC, scaled);
        gemm_bt_mfma<2048, 512, 2><<<dim3(8, 32, 2), 256, 0, stream>>>(
            scaled, W0bf + (size_t)i * 512 * 2048, ybufp);
        ln_lrelu_kernel<<<1024, 256, 0, stream>>>(
            ybufp, ybufp + (size_t)TT * 512, b0 + i * DD, g0 + i * DD, be0 + i * DD,
            zbuf_bf, nullptr, nullptr, nullptr);
        gemm_bt_mfma<512, 512, 2><<<dim3(8, 32, 2), 256, 0, stream>>>(
            zbuf_bf, W1bf + (size_t)i * 512 * 512, ybufp);
        ln_lrelu_kernel<<<1024, 256, 0, stream>>>(
            ybufp, ybufp + (size_t)TT * 512, b1 + i * DD, g1 + i * DD, be1 + i * DD,
            nullptr,
            (i < LL - 1) ? x : nullptr,
            (i < LL - 1) ? h_bf : nullptr,
            (i == LL - 1) ? out : nullptr);
    }
}

// Round 13
// 184.941 us; speedup vs baseline: 1.5032x; 1.0598x over previous
//
#include <hip/hip_runtime.h>
#include <math.h>

// Problem constants
#define TT 4096
#define DD 512
#define RR 32
#define CC 32
#define RC 1024
#define LL 2
#define CHUNK 32
#define NCHUNK 128
#define NEG_SLOPE 0.01f
#define LN_EPS 1e-5f

typedef __attribute__((ext_vector_type(8))) __bf16 bf16x8;
typedef __attribute__((ext_vector_type(4))) float f32x4;

__device__ __forceinline__ unsigned short f2bf(float f) {
    unsigned int u = __builtin_bit_cast(unsigned int, f);
    u += 0x7fffu + ((u >> 16) & 1u);   // round-to-nearest-even
    return (unsigned short)(u >> 16);
}

// ---------------------------------------------------------------------------
// Fused setup: f32->bf16 for x, W0, W1, plus Wt/Wc pack into Wtc[L,64,512].
#define NX4  524288   // 4096*512/4
#define NW04 524288   // 2*512*2048/4
#define NW14 131072   // 2*512*512/4
#define NCV  (NX4 + NW04 + NW14)
#define NPK  16384    // 2*64*512/4
__global__ __launch_bounds__(256) void setup_kernel(const float4* __restrict__ x,
                                                    const float4* __restrict__ W0,
                                                    const float4* __restrict__ W1,
                                                    const float* __restrict__ Wt,
                                                    const float* __restrict__ Wc,
                                                    ushort4* __restrict__ xb,
                                                    ushort4* __restrict__ W0b,
                                                    ushort4* __restrict__ W1b,
                                                    ushort4* __restrict__ Wtc) {
    int i = blockIdx.x * 256 + threadIdx.x;
    float4 v;
    ushort4* dst;
    int j;
    if (i < NCV) {
        const float4* src;
        if (i < NX4) { src = x; dst = xb; j = i; }
        else if (i < NX4 + NW04) { src = W0; dst = W0b; j = i - NX4; }
        else { src = W1; dst = W1b; j = i - NX4 - NW04; }
        v = src[j];
    } else {
        int ii = i - NCV;
        if (ii >= NPK) return;
        int e = ii * 4;
        int l = e >> 15;
        int r = (e >> 9) & 63;
        int k = e & 511;
        v = (r < 32) ? *(const float4*)&Wt[((size_t)l * 32 + r) * 512 + k]
                     : *(const float4*)&Wc[((size_t)l * 32 + (r - 32)) * 512 + k];
        dst = Wtc; j = ii;
    }
    ushort4 o;
    o.x = f2bf(v.x); o.y = f2bf(v.y); o.z = f2bf(v.z); o.w = f2bf(v.w);
    dst[j] = o;
}

// ---------------------------------------------------------------------------
// proj + denom fused (R7 proven): tcabs[t,r]=|tr_r|*invd (r<32); tcabs[t,32+c]=|ct_c|
__global__ __launch_bounds__(256) void proj_denom_kernel(const unsigned short* __restrict__ A,
                                                         const unsigned short* __restrict__ B,
                                                         float* __restrict__ tcabs) {
    __shared__ __align__(16) unsigned short As[64 * 32];
    __shared__ __align__(16) unsigned short Bs[64 * 32];
    const int tid = threadIdx.x;
    const int w = tid >> 6, lane = tid & 63;
    const int bm = blockIdx.x * 64;
    const int K = 512;
    const int srow = tid >> 2;           // 0..63
    const int sl = tid & 3;              // 16B slot
    const int sswz = (sl ^ ((srow >> 1) & 3)) * 8;
    const unsigned short* gA = A + (size_t)(bm + srow) * K + sl * 8;
    const unsigned short* gB = B + (size_t)srow * K + sl * 8;
    const int wA = srow * 32 + sswz;
    const int wB = srow * 32 + sswz;
    const int fr = lane & 15, hi = lane >> 4;
    const int kslot = hi ^ ((fr >> 1) & 3);
    f32x4 acc0 = {}, acc1 = {}, acc2 = {}, acc3 = {};

    uint4 va = *(const uint4*)gA;
    uint4 vb = *(const uint4*)gB;
    for (int k0 = 0; k0 < K; k0 += 32) {
        __syncthreads();
        *(uint4*)&As[wA] = va;
        *(uint4*)&Bs[wB] = vb;
        __syncthreads();
        if (k0 + 32 < K) {
            va = *(const uint4*)(gA + k0 + 32);
            vb = *(const uint4*)(gB + k0 + 32);
        }
        const int arow = w * 16 + fr;
        bf16x8 af = *(const bf16x8*)&As[arow * 32 + kslot * 8];
        bf16x8 b0 = *(const bf16x8*)&Bs[(0 * 16 + fr) * 32 + kslot * 8];
        bf16x8 b1 = *(const bf16x8*)&Bs[(1 * 16 + fr) * 32 + kslot * 8];
        bf16x8 b2 = *(const bf16x8*)&Bs[(2 * 16 + fr) * 32 + kslot * 8];
        bf16x8 b3 = *(const bf16x8*)&Bs[(3 * 16 + fr) * 32 + kslot * 8];
        acc0 = __builtin_amdgcn_mfma_f32_16x16x32_bf16(af, b0, acc0, 0, 0, 0);
        acc1 = __builtin_amdgcn_mfma_f32_16x16x32_bf16(af, b1, acc1, 0, 0, 0);
        acc2 = __builtin_amdgcn_mfma_f32_16x16x32_bf16(af, b2, acc2, 0, 0, 0);
        acc3 = __builtin_amdgcn_mfma_f32_16x16x32_bf16(af, b3, acc3, 0, 0, 0);
    }
#pragma unroll
    for (int q = 0; q < 4; ++q) {
        float a0 = fabsf(acc0[q]), a1 = fabsf(acc1[q]);
        float a2 = fabsf(acc2[q]), a3 = fabsf(acc3[q]);
        float st = a0 + a1, sc = a2 + a3;
        st += __shfl_xor(st, 1); sc += __shfl_xor(sc, 1);
        st += __shfl_xor(st, 2); sc += __shfl_xor(sc, 2);
        st += __shfl_xor(st, 4); sc += __shfl_xor(sc, 4);
        st += __shfl_xor(st, 8); sc += __shfl_xor(sc, 8);
        float inv = 1.f / (1e-8f + st * sc);
        size_t rb = (size_t)(bm + w * 16 + hi * 4 + q) * 64;
        tcabs[rb + fr]      = a0 * inv;
        tcabs[rb + fr + 16] = a1 * inv;
        tcabs[rb + fr + 32] = a2;
        tcabs[rb + fr + 48] = a3;
    }
}

// ---------------------------------------------------------------------------
// Scan pass 1: per (chunk, r, c) affine transform (alpha, beta) with resets.
__global__ __launch_bounds__(256) void scan_pass1(const float* __restrict__ tcabs,
                                                  const int* __restrict__ start,
                                                  const float* __restrict__ a,
                                                  const float* __restrict__ b,
                                                  float4* __restrict__ ab4) {
    int tid = blockIdx.x * 256 + threadIdx.x;   // NCHUNK*RC = 131072
    int rc = tid & (RC - 1);
    int chunk = tid >> 10;
    int r = rc >> 5, c = rc & 31;
    float e = expf(-fabsf(a[r]));
    float gr = e * cosf(b[c]);
    float gi = e * sinf(b[c]);
    float alr = 1.f, ali = 0.f, ber = 0.f, bei = 0.f;
    int t0 = chunk * CHUNK;
    for (int j = 0; j < CHUNK; ++j) {
        int t = t0 + j;
        float pre = tcabs[t * 64 + r] * tcabs[t * 64 + 32 + c];
        if (start[t]) {
            alr = 0.f; ali = 0.f; ber = pre; bei = 0.f;
        } else {
            float nbr = pre + gr * ber - gi * bei;
            float nbi =       gr * bei + gi * ber;
            float nar = gr * alr - gi * ali;
            float nai = gr * ali + gi * alr;
            ber = nbr; bei = nbi; alr = nar; ali = nai;
        }
    }
    ab4[chunk * RC + rc] = make_float4(alr, ali, ber, bei);
}

// ---------------------------------------------------------------------------
// Scan pass 2 + in-block lookback: compose ab4[0..chunk-1] (8-deep prefetch),
// then rescan own chunk, emit scaled features (bf16).
// grid 512: chunk = bx>>2, rc = (bx&3)*256 + tx.
__global__ __launch_bounds__(256) void scan_pass2f(const float* __restrict__ tcabs,
                                                   const float4* __restrict__ ab4,
                                                   const int* __restrict__ start,
                                                   const float* __restrict__ a,
                                                   const float* __restrict__ b,
                                                   const float* __restrict__ s0r,
                                                   const float* __restrict__ s0i,
                                                   unsigned short* __restrict__ scaled) {
    int bx = blockIdx.x;
    int chunk = bx >> 2;
    int rc = (bx & 3) * 256 + threadIdx.x;
    int r = rc >> 5, c = rc & 31;
    float e = expf(-fabsf(a[r]));
    float gr = e * cosf(b[c]);
    float gi = e * sinf(b[c]);
    float sr = s0r[rc], si = s0i[rc];
    int j = 0;
    for (; j + 8 <= chunk; j += 8) {
        float4 buf[8];
#pragma unroll
        for (int u = 0; u < 8; ++u) buf[u] = ab4[(j + u) * RC + rc];
#pragma unroll
        for (int u = 0; u < 8; ++u) {
            float nsr = buf[u].z + buf[u].x * sr - buf[u].y * si;
            float nsi = buf[u].w + buf[u].x * si + buf[u].y * sr;
            sr = nsr; si = nsi;
        }
    }
    for (; j < chunk; ++j) {
        float4 ab = ab4[j * RC + rc];
        float nsr = ab.z + ab.x * sr - ab.y * si;
        float nsi = ab.w + ab.x * si + ab.y * sr;
        sr = nsr; si = nsi;
    }
    int t0 = chunk * CHUNK;
    for (int jj = 0; jj < CHUNK; ++jj) {
        int t = t0 + jj;
        float pre = tcabs[t * 64 + r] * tcabs[t * 64 + 32 + c];
        if (start[t]) {
            sr = pre; si = 0.f;
        } else {
            float nsr = pre + gr * sr - gi * si;
            float nsi =       gr * si + gi * sr;
            sr = nsr; si = nsi;
        }
        float m = sqrtf(sr * sr + si * si);
        float mag = log1pf(m);
        float f = (m > 0.f) ? (mag / m) : 0.f;
        scaled[(size_t)t * 2048 + rc]        = f2bf(si * f);
        scaled[(size_t)t * 2048 + 1024 + rc] = f2bf(sr * f);
    }
}

// ---------------------------------------------------------------------------
// Cm_partial[z][4096,N] = A[4096,Kz]bf16 @ B[N,Kz]bf16^T  (split-K partials)
// Tile 128x64, BK=64, 4 waves. Fully-NAMED-scalar staging (no arrays — the
// R5 scratch-spill lesson): per thread 4 A-vecs + 2 B-vecs at row offsets
// {0,32,64,96}/{0,32}, one shared swizzle slot k8^(srow&7) (row offsets are
// multiples of 32 so row&7 is invariant). Read slot ks^(row&7) — the R5
// pattern that measured SQ_LDS_BANK_CONFLICT = 0. XCD-chunked block swizzle.
template <int K, int N, int SPLITK>
__global__ __launch_bounds__(256) void gemm_bt_mfma(const unsigned short* __restrict__ A,
                                                    const unsigned short* __restrict__ B,
                                                    float* __restrict__ Cm) {
    __shared__ __align__(16) unsigned short As[128 * 64];
    __shared__ __align__(16) unsigned short Bs[64 * 64];
    const int tid = threadIdx.x;
    const int w = tid >> 6, lane = tid & 63;
    const int nwg = gridDim.x * gridDim.y * gridDim.z;
    const int id = blockIdx.x + gridDim.x * (blockIdx.y + gridDim.y * blockIdx.z);
    const int lid = (id & 7) * (nwg >> 3) + (id >> 3);
    const int bxs = lid % gridDim.x;
    const int t2 = lid / gridDim.x;
    const int bys = t2 % gridDim.y;
    const int bzs = t2 / gridDim.y;
    const int bm = bys * 128, bn = bxs * 64;
    const int kbeg = bzs * (K / SPLITK);
    const int kend = kbeg + (K / SPLITK);
    const int wr = w >> 1, wc = w & 1;
    // staging addressing (named scalars only)
    const int srow = tid >> 3;               // 0..31
    const int k8 = tid & 7;                  // 16B slot in BK=64 row
    const int swz = (k8 ^ (srow & 7)) * 8;   // same for all 4 vecs
    const unsigned short* gA = A + (size_t)(bm + srow) * K + k8 * 8;
    const unsigned short* gB = B + (size_t)(bn + srow) * K + k8 * 8;
    const int wAb = srow * 64 + swz;
    const int fr = lane & 15, hi = lane >> 4;
    f32x4 acc[4][2] = {};

    uint4 va0 = *(const uint4*)(gA + kbeg);
    uint4 va1 = *(const uint4*)(gA + (size_t)32 * K + kbeg);
    uint4 va2 = *(const uint4*)(gA + (size_t)64 * K + kbeg);
    uint4 va3 = *(const uint4*)(gA + (size_t)96 * K + kbeg);
    uint4 vb0 = *(const uint4*)(gB + kbeg);
    uint4 vb1 = *(const uint4*)(gB + (size_t)32 * K + kbeg);
    for (int k0 = kbeg; k0 < kend; k0 += 64) {
        __syncthreads();
        *(uint4*)&As[wAb]        = va0;
        *(uint4*)&As[wAb + 2048] = va1;
        *(uint4*)&As[wAb + 4096] = va2;
        *(uint4*)&As[wAb + 6144] = va3;
        *(uint4*)&Bs[wAb]        = vb0;
        *(uint4*)&Bs[wAb + 2048] = vb1;
        __syncthreads();
        if (k0 + 64 < kend) {
            va0 = *(const uint4*)(gA + k0 + 64);
            va1 = *(const uint4*)(gA + (size_t)32 * K + k0 + 64);
            va2 = *(const uint4*)(gA + (size_t)64 * K + k0 + 64);
            va3 = *(const uint4*)(gA + (size_t)96 * K + k0 + 64);
            vb0 = *(const uint4*)(gB + k0 + 64);
            vb1 = *(const uint4*)(gB + (size_t)32 * K + k0 + 64);
        }
#pragma unroll
        for (int kk = 0; kk < 2; ++kk) {
            const int ks = kk * 4 + hi;      // 0..7
            bf16x8 af[4], bfv[2];
#pragma unroll
            for (int mi = 0; mi < 4; ++mi) {
                int row = wr * 64 + mi * 16 + fr;
                af[mi] = *(const bf16x8*)&As[row * 64 + ((ks ^ (row & 7)) * 8)];
            }
#pragma unroll
            for (int ni = 0; ni < 2; ++ni) {
                int row = wc * 32 + ni * 16 + fr;
                bfv[ni] = *(const bf16x8*)&Bs[row * 64 + ((ks ^ (row & 7)) * 8)];
            }
#pragma unroll
            for (int mi = 0; mi < 4; ++mi)
#pragma unroll
                for (int ni = 0; ni < 2; ++ni)
                    acc[mi][ni] = __builtin_amdgcn_mfma_f32_16x16x32_bf16(
                        af[mi], bfv[ni], acc[mi][ni], 0, 0, 0);
        }
    }
    // epilogue: C/D layout col=lane&15, row=(lane>>4)*4+reg  [m89]
    float* Cz = Cm + (size_t)bzs * TT * N;
    const int ccol0 = bn + wc * 32 + fr;
    const int crow0 = bm + wr * 64 + hi * 4;
#pragma unroll
    for (int ni = 0; ni < 2; ++ni) {
        int col = ccol0 + ni * 16;
#pragma unroll
        for (int mi = 0; mi < 4; ++mi)
#pragma unroll
            for (int q = 0; q < 4; ++q)
                Cz[(size_t)(crow0 + mi * 16 + q) * N + col] = acc[mi][ni][q];
    }
}

// ---------------------------------------------------------------------------
// Wave-per-row LayerNorm + LeakyReLU (R12 proven): y = y0 + y1 + bias.
// grid 1024 x 256 thr; wave owns one row, lane covers 8 cols (16B loads).
__global__ __launch_bounds__(256) void ln_lrelu_kernel(const float* __restrict__ y0,
                                                       const float* __restrict__ y1,
                                                       const float* __restrict__ badd,
                                                       const float* __restrict__ g,
                                                       const float* __restrict__ be,
                                                       unsigned short* __restrict__ zb,
                                                       const float* __restrict__ res,
                                                       unsigned short* __restrict__ hbf,
                                                       float* __restrict__ fout) {
    const int lane = threadIdx.x & 63;
    const int row = blockIdx.x * 4 + (threadIdx.x >> 6);
    const size_t base = (size_t)row * 512 + lane * 8;
    const int cb = lane * 8;
    float4 p0a = *(const float4*)&y0[base];
    float4 p0b = *(const float4*)&y0[base + 4];
    float4 p1a = *(const float4*)&y1[base];
    float4 p1b = *(const float4*)&y1[base + 4];
    float4 ba = *(const float4*)&badd[cb];
    float4 bb = *(const float4*)&badd[cb + 4];
    float v[8];
    v[0] = p0a.x + p1a.x + ba.x; v[1] = p0a.y + p1a.y + ba.y;
    v[2] = p0a.z + p1a.z + ba.z; v[3] = p0a.w + p1a.w + ba.w;
    v[4] = p0b.x + p1b.x + bb.x; v[5] = p0b.y + p1b.y + bb.y;
    v[6] = p0b.z + p1b.z + bb.z; v[7] = p0b.w + p1b.w + bb.w;
    float s = 0.f, ss = 0.f;
#pragma unroll
    for (int j = 0; j < 8; ++j) { s += v[j]; ss += v[j] * v[j]; }
#pragma unroll
    for (int o = 1; o < 64; o <<= 1) {
        s  += __shfl_xor(s, o);
        ss += __shfl_xor(ss, o);
    }
    float m = s * (1.f / 512.f);
    float rs = rsqrtf(ss * (1.f / 512.f) - m * m + LN_EPS);
    float4 ga = *(const float4*)&g[cb];
    float4 gb = *(const float4*)&g[cb + 4];
    float4 ea = *(const float4*)&be[cb];
    float4 eb = *(const float4*)&be[cb + 4];
    float gg[8] = {ga.x, ga.y, ga.z, ga.w, gb.x, gb.y, gb.z, gb.w};
    float ee[8] = {ea.x, ea.y, ea.z, ea.w, eb.x, eb.y, eb.z, eb.w};
    float z[8];
#pragma unroll
    for (int j = 0; j < 8; ++j) {
        float zz = gg[j] * (v[j] - m) * rs + ee[j];
        z[j] = (zz > 0.f) ? zz : NEG_SLOPE * zz;
    }
    if (zb) {
        ushort4 o0, o1;
        o0.x = f2bf(z[0]); o0.y = f2bf(z[1]); o0.z = f2bf(z[2]); o0.w = f2bf(z[3]);
        o1.x = f2bf(z[4]); o1.y = f2bf(z[5]); o1.z = f2bf(z[6]); o1.w = f2bf(z[7]);
        *(ushort4*)&zb[base] = o0;
        *(ushort4*)&zb[base + 4] = o1;
    }
    if (hbf) {
        float4 ra = *(const float4*)&res[base];
        float4 rb2 = *(const float4*)&res[base + 4];
        ushort4 o0, o1;
        o0.x = f2bf(ra.x + z[0]); o0.y = f2bf(ra.y + z[1]);
        o0.z = f2bf(ra.z + z[2]); o0.w = f2bf(ra.w + z[3]);
        o1.x = f2bf(rb2.x + z[4]); o1.y = f2bf(rb2.y + z[5]);
        o1.z = f2bf(rb2.z + z[6]); o1.w = f2bf(rb2.w + z[7]);
        *(ushort4*)&hbf[base] = o0;
        *(ushort4*)&hbf[base + 4] = o1;
    }
    if (fout) {
        *(float4*)&fout[base] = make_float4(z[0], z[1], z[2], z[3]);
        *(float4*)&fout[base + 4] = make_float4(z[4], z[5], z[6], z[7]);
    }
}

// ---------------------------------------------------------------------------
extern "C" void kernel_launch(void* const* d_in, const int* in_sizes, int n_in,
                              void* d_out, int out_size, void* d_ws, size_t ws_size,
                              hipStream_t stream) {
    const float* x     = (const float*)d_in[0];
    const int*   start = (const int*)d_in[1];
    const float* s0r = (const float*)d_in[3];
    const float* s0i = (const float*)d_in[4];
    const float* Wt  = (const float*)d_in[5];
    const float* Wc  = (const float*)d_in[6];
    const float* a   = (const float*)d_in[7];
    const float* b   = (const float*)d_in[8];
    const float* W0  = (const float*)d_in[9];
    const float* b0  = (const float*)d_in[10];
    const float* g0  = (const float*)d_in[11];
    const float* be0 = (const float*)d_in[12];
    const float* W1  = (const float*)d_in[13];
    const float* b1  = (const float*)d_in[14];
    const float* g1  = (const float*)d_in[15];
    const float* be1 = (const float*)d_in[16];
    float* out = (float*)d_out;
    float* ws  = (float*)d_ws;

    // workspace layout (float-unit offsets, all 16B aligned)  ~50 MB
    float* p = ws;
    float* tcabs  = p; p += 262144;                  // [4096][64] f32 (invd folded)
    float4* ab4   = (float4*)p; p += 524288;         // [128][1024] float4
    unsigned short* scaled = (unsigned short*)p; p += 4194304;   // [4096][2048] bf16
    float* ybufp  = p; p += 4194304;                 // [2][4096][512] f32 partials
    unsigned short* zbuf_bf = (unsigned short*)p; p += 1048576;  // [4096][512] bf16
    unsigned short* x_bf    = (unsigned short*)p; p += 1048576;
    unsigned short* h_bf    = (unsigned short*)p; p += 1048576;
    unsigned short* Wtcbf   = (unsigned short*)p; p += 32768;    // [2][64][512] bf16
    unsigned short* W0bf    = (unsigned short*)p; p += 1048576;  // [2][512][2048] bf16
    unsigned short* W1bf    = (unsigned short*)p; p += 262144;   // [2][512][512] bf16

    setup_kernel<<<(NCV + NPK + 255) / 256, 256, 0, stream>>>(
        (const float4*)x, (const float4*)W0, (const float4*)W1, Wt, Wc,
        (ushort4*)x_bf, (ushort4*)W0bf, (ushort4*)W1bf, (ushort4*)Wtcbf);

    for (int i = 0; i < LL; ++i) {
        const unsigned short* hb = (i == 0) ? x_bf : h_bf;
        proj_denom_kernel<<<64, 256, 0, stream>>>(
            hb, Wtcbf + (size_t)i * 64 * 512, tcabs);
        scan_pass1<<<NCHUNK * RC / 256, 256, 0, stream>>>(
            tcabs, start, a + i * RR, b + i * CC, ab4);
        scan_pass2f<<<NCHUNK * 4, 256, 0, stream>>>(
            tcabs, ab4, start, a + i * RR, b + i * CC,
            s0r + i * RC, s0i + i * RC, scaled);
        gemm_bt_mfma<2048, 512, 2><<<dim3(8, 32, 2), 256, 0, stream>>>(
            scaled, W0bf + (size_t)i * 512 * 2048, ybufp);
        ln_lrelu_kernel<<<1024, 256, 0, stream>>>(
            ybufp, ybufp + (size_t)TT * 512, b0 + i * DD, g0 + i * DD, be0 + i * DD,
            zbuf_bf, nullptr, nullptr, nullptr);
        gemm_bt_mfma<512, 512, 2><<<dim3(8, 32, 2), 256, 0, stream>>>(
            zbuf_bf, W1bf + (size_t)i * 512 * 512, ybufp);
        ln_lrelu_kernel<<<1024, 256, 0, stream>>>(
            ybufp, ybufp + (size_t)TT * 512, b1 + i * DD, g1 + i * DD, be1 + i * DD,
            nullptr,
            (i < LL - 1) ? x : nullptr,
            (i < LL - 1) ? h_bf : nullptr,
            (i == LL - 1) ? out : nullptr);
    }
}

// Round 14
// 178.463 us; speedup vs baseline: 1.5578x; 1.0363x over previous
//
#include <hip/hip_runtime.h>
#include <math.h>

// Problem constants
#define TT 4096
#define DD 512
#define RR 32
#define CC 32
#define RC 1024
#define LL 2
#define CHUNK 32
#define NCHUNK 128
#define NEG_SLOPE 0.01f
#define LN_EPS 1e-5f

typedef __attribute__((ext_vector_type(8))) __bf16 bf16x8;
typedef __attribute__((ext_vector_type(4))) float f32x4;

__device__ __forceinline__ unsigned short f2bf(float f) {
    unsigned int u = __builtin_bit_cast(unsigned int, f);
    u += 0x7fffu + ((u >> 16) & 1u);   // round-to-nearest-even
    return (unsigned short)(u >> 16);
}
__device__ __forceinline__ float bf2f(unsigned short s) {
    unsigned int u = (unsigned int)s << 16;
    return __builtin_bit_cast(float, u);
}

// ---------------------------------------------------------------------------
// Fused setup: f32->bf16 for x, W0, W1, plus Wt/Wc pack into Wtc[L,64,512].
#define NX4  524288   // 4096*512/4
#define NW04 524288   // 2*512*2048/4
#define NW14 131072   // 2*512*512/4
#define NCV  (NX4 + NW04 + NW14)
#define NPK  16384    // 2*64*512/4
__global__ __launch_bounds__(256) void setup_kernel(const float4* __restrict__ x,
                                                    const float4* __restrict__ W0,
                                                    const float4* __restrict__ W1,
                                                    const float* __restrict__ Wt,
                                                    const float* __restrict__ Wc,
                                                    ushort4* __restrict__ xb,
                                                    ushort4* __restrict__ W0b,
                                                    ushort4* __restrict__ W1b,
                                                    ushort4* __restrict__ Wtc) {
    int i = blockIdx.x * 256 + threadIdx.x;
    float4 v;
    ushort4* dst;
    int j;
    if (i < NCV) {
        const float4* src;
        if (i < NX4) { src = x; dst = xb; j = i; }
        else if (i < NX4 + NW04) { src = W0; dst = W0b; j = i - NX4; }
        else { src = W1; dst = W1b; j = i - NX4 - NW04; }
        v = src[j];
    } else {
        int ii = i - NCV;
        if (ii >= NPK) return;
        int e = ii * 4;
        int l = e >> 15;
        int r = (e >> 9) & 63;
        int k = e & 511;
        v = (r < 32) ? *(const float4*)&Wt[((size_t)l * 32 + r) * 512 + k]
                     : *(const float4*)&Wc[((size_t)l * 32 + (r - 32)) * 512 + k];
        dst = Wtc; j = ii;
    }
    ushort4 o;
    o.x = f2bf(v.x); o.y = f2bf(v.y); o.z = f2bf(v.z); o.w = f2bf(v.w);
    dst[j] = o;
}

// ---------------------------------------------------------------------------
// proj + denom fused: tcabs[t,r]=|tr_r|*invd (r<32); tcabs[t,32+c]=|ct_c|.
// Tile 64(M)x64(N), BK=64, 4 waves; wave w owns rows w*16..w*16+15 (1x4 frags).
// Named-scalar staging (2 A-vecs + 2 B-vecs/thread), slot swz = k8^(srow&7),
// read slot ks^(row&7) (the R5/R13 pattern, measured 0 bank conflicts). grid 64.
__global__ __launch_bounds__(256) void proj_denom_kernel(const unsigned short* __restrict__ A,
                                                         const unsigned short* __restrict__ B,
                                                         float* __restrict__ tcabs) {
    __shared__ __align__(16) unsigned short As[64 * 64];
    __shared__ __align__(16) unsigned short Bs[64 * 64];
    const int tid = threadIdx.x;
    const int w = tid >> 6, lane = tid & 63;
    const int bm = blockIdx.x * 64;
    const int K = 512;
    const int srow = tid >> 3;               // 0..31
    const int k8 = tid & 7;                  // 16B slot in BK=64 row
    const int swz = (k8 ^ (srow & 7)) * 8;   // (srow+32)&7 == srow&7
    const unsigned short* gA = A + (size_t)(bm + srow) * K + k8 * 8;
    const unsigned short* gB = B + (size_t)srow * K + k8 * 8;
    const int wb = srow * 64 + swz;
    const int fr = lane & 15, hi = lane >> 4;
    f32x4 acc0 = {}, acc1 = {}, acc2 = {}, acc3 = {};

    uint4 va0 = *(const uint4*)gA;
    uint4 va1 = *(const uint4*)(gA + (size_t)32 * K);
    uint4 vb0 = *(const uint4*)gB;
    uint4 vb1 = *(const uint4*)(gB + (size_t)32 * K);
    for (int k0 = 0; k0 < K; k0 += 64) {
        __syncthreads();
        *(uint4*)&As[wb]        = va0;
        *(uint4*)&As[wb + 2048] = va1;
        *(uint4*)&Bs[wb]        = vb0;
        *(uint4*)&Bs[wb + 2048] = vb1;
        __syncthreads();
        if (k0 + 64 < K) {
            va0 = *(const uint4*)(gA + k0 + 64);
            va1 = *(const uint4*)(gA + (size_t)32 * K + k0 + 64);
            vb0 = *(const uint4*)(gB + k0 + 64);
            vb1 = *(const uint4*)(gB + (size_t)32 * K + k0 + 64);
        }
        const int arow = w * 16 + fr;
#pragma unroll
        for (int kk = 0; kk < 2; ++kk) {
            const int ks = kk * 4 + hi;      // 0..7
            bf16x8 af = *(const bf16x8*)&As[arow * 64 + ((ks ^ (arow & 7)) * 8)];
            bf16x8 b0 = *(const bf16x8*)&Bs[(0 * 16 + fr) * 64 + ((ks ^ (fr & 7)) * 8)];
            bf16x8 b1 = *(const bf16x8*)&Bs[(1 * 16 + fr) * 64 + ((ks ^ (fr & 7)) * 8)];
            bf16x8 b2 = *(const bf16x8*)&Bs[(2 * 16 + fr) * 64 + ((ks ^ (fr & 7)) * 8)];
            bf16x8 b3 = *(const bf16x8*)&Bs[(3 * 16 + fr) * 64 + ((ks ^ (fr & 7)) * 8)];
            acc0 = __builtin_amdgcn_mfma_f32_16x16x32_bf16(af, b0, acc0, 0, 0, 0);
            acc1 = __builtin_amdgcn_mfma_f32_16x16x32_bf16(af, b1, acc1, 0, 0, 0);
            acc2 = __builtin_amdgcn_mfma_f32_16x16x32_bf16(af, b2, acc2, 0, 0, 0);
            acc3 = __builtin_amdgcn_mfma_f32_16x16x32_bf16(af, b3, acc3, 0, 0, 0);
        }
    }
#pragma unroll
    for (int q = 0; q < 4; ++q) {
        float a0 = fabsf(acc0[q]), a1 = fabsf(acc1[q]);
        float a2 = fabsf(acc2[q]), a3 = fabsf(acc3[q]);
        float st = a0 + a1, sc = a2 + a3;
        st += __shfl_xor(st, 1); sc += __shfl_xor(sc, 1);
        st += __shfl_xor(st, 2); sc += __shfl_xor(sc, 2);
        st += __shfl_xor(st, 4); sc += __shfl_xor(sc, 4);
        st += __shfl_xor(st, 8); sc += __shfl_xor(sc, 8);
        float inv = 1.f / (1e-8f + st * sc);
        size_t rb = (size_t)(bm + w * 16 + hi * 4 + q) * 64;
        tcabs[rb + fr]      = a0 * inv;
        tcabs[rb + fr + 16] = a1 * inv;
        tcabs[rb + fr + 32] = a2;
        tcabs[rb + fr + 48] = a3;
    }
}

// ---------------------------------------------------------------------------
// Scan pass 1: per (chunk, r, c) affine transform (alpha, beta) with resets.
__global__ __launch_bounds__(256) void scan_pass1(const float* __restrict__ tcabs,
                                                  const int* __restrict__ start,
                                                  const float* __restrict__ a,
                                                  const float* __restrict__ b,
                                                  float4* __restrict__ ab4) {
    int tid = blockIdx.x * 256 + threadIdx.x;   // NCHUNK*RC = 131072
    int rc = tid & (RC - 1);
    int chunk = tid >> 10;
    int r = rc >> 5, c = rc & 31;
    float e = expf(-fabsf(a[r]));
    float gr = e * cosf(b[c]);
    float gi = e * sinf(b[c]);
    float alr = 1.f, ali = 0.f, ber = 0.f, bei = 0.f;
    int t0 = chunk * CHUNK;
    for (int j = 0; j < CHUNK; ++j) {
        int t = t0 + j;
        float pre = tcabs[t * 64 + r] * tcabs[t * 64 + 32 + c];
        if (start[t]) {
            alr = 0.f; ali = 0.f; ber = pre; bei = 0.f;
        } else {
            float nbr = pre + gr * ber - gi * bei;
            float nbi =       gr * bei + gi * ber;
            float nar = gr * alr - gi * ali;
            float nai = gr * ali + gi * alr;
            ber = nbr; bei = nbi; alr = nar; ali = nai;
        }
    }
    ab4[chunk * RC + rc] = make_float4(alr, ali, ber, bei);
}

// ---------------------------------------------------------------------------
// Scan pass 2 + in-block lookback: compose ab4[0..chunk-1] (8-deep prefetch),
// then rescan own chunk, emit scaled features (bf16).
// grid 512; cid = bx>>2 is remapped light/heavy-interleaved for load balance.
__global__ __launch_bounds__(256) void scan_pass2f(const float* __restrict__ tcabs,
                                                   const float4* __restrict__ ab4,
                                                   const int* __restrict__ start,
                                                   const float* __restrict__ a,
                                                   const float* __restrict__ b,
                                                   const float* __restrict__ s0r,
                                                   const float* __restrict__ s0i,
                                                   unsigned short* __restrict__ scaled) {
    int bx = blockIdx.x;
    int cid = bx >> 2;
    int chunk = (cid & 1) ? (NCHUNK - 1 - (cid >> 1)) : (cid >> 1);
    int rc = (bx & 3) * 256 + threadIdx.x;
    int r = rc >> 5, c = rc & 31;
    float e = expf(-fabsf(a[r]));
    float gr = e * cosf(b[c]);
    float gi = e * sinf(b[c]);
    float sr = s0r[rc], si = s0i[rc];
    int j = 0;
    for (; j + 8 <= chunk; j += 8) {
        float4 buf[8];
#pragma unroll
        for (int u = 0; u < 8; ++u) buf[u] = ab4[(j + u) * RC + rc];
#pragma unroll
        for (int u = 0; u < 8; ++u) {
            float nsr = buf[u].z + buf[u].x * sr - buf[u].y * si;
            float nsi = buf[u].w + buf[u].x * si + buf[u].y * sr;
            sr = nsr; si = nsi;
        }
    }
    for (; j < chunk; ++j) {
        float4 ab = ab4[j * RC + rc];
        float nsr = ab.z + ab.x * sr - ab.y * si;
        float nsi = ab.w + ab.x * si + ab.y * sr;
        sr = nsr; si = nsi;
    }
    int t0 = chunk * CHUNK;
    for (int jj = 0; jj < CHUNK; ++jj) {
        int t = t0 + jj;
        float pre = tcabs[t * 64 + r] * tcabs[t * 64 + 32 + c];
        if (start[t]) {
            sr = pre; si = 0.f;
        } else {
            float nsr = pre + gr * sr - gi * si;
            float nsi =       gr * si + gi * sr;
            sr = nsr; si = nsi;
        }
        float m2 = sr * sr + si * si;
        float rsq = rsqrtf(m2);
        float m = m2 * rsq;                    // |s|
        float f = (m2 > 0.f) ? log1pf(m) * rsq : 0.f;   // log1p(|s|)/|s|
        scaled[(size_t)t * 2048 + rc]        = f2bf(si * f);
        scaled[(size_t)t * 2048 + 1024 + rc] = f2bf(sr * f);
    }
}

// ---------------------------------------------------------------------------
// Cm_partial[z][4096,N] = A[4096,Kz]bf16 @ B[N,Kz]bf16^T, stored as BF16
// (LN re-sums in fp32). Tile 128x64, BK=64, 4 waves, named-scalar staging
// (R13 champion). XCD-chunked block swizzle (bijective since nwg % 8 == 0).
template <int K, int N, int SPLITK>
__global__ __launch_bounds__(256) void gemm_bt_mfma(const unsigned short* __restrict__ A,
                                                    const unsigned short* __restrict__ B,
                                                    unsigned short* __restrict__ Cm) {
    __shared__ __align__(16) unsigned short As[128 * 64];
    __shared__ __align__(16) unsigned short Bs[64 * 64];
    const int tid = threadIdx.x;
    const int w = tid >> 6, lane = tid & 63;
    const int nwg = gridDim.x * gridDim.y * gridDim.z;
    const int id = blockIdx.x + gridDim.x * (blockIdx.y + gridDim.y * blockIdx.z);
    const int lid = (id & 7) * (nwg >> 3) + (id >> 3);
    const int bxs = lid % gridDim.x;
    const int t2 = lid / gridDim.x;
    const int bys = t2 % gridDim.y;
    const int bzs = t2 / gridDim.y;
    const int bm = bys * 128, bn = bxs * 64;
    const int kbeg = bzs * (K / SPLITK);
    const int kend = kbeg + (K / SPLITK);
    const int wr = w >> 1, wc = w & 1;
    const int srow = tid >> 3;               // 0..31
    const int k8 = tid & 7;
    const int swz = (k8 ^ (srow & 7)) * 8;
    const unsigned short* gA = A + (size_t)(bm + srow) * K + k8 * 8;
    const unsigned short* gB = B + (size_t)(bn + srow) * K + k8 * 8;
    const int wAb = srow * 64 + swz;
    const int fr = lane & 15, hi = lane >> 4;
    f32x4 acc[4][2] = {};

    uint4 va0 = *(const uint4*)(gA + kbeg);
    uint4 va1 = *(const uint4*)(gA + (size_t)32 * K + kbeg);
    uint4 va2 = *(const uint4*)(gA + (size_t)64 * K + kbeg);
    uint4 va3 = *(const uint4*)(gA + (size_t)96 * K + kbeg);
    uint4 vb0 = *(const uint4*)(gB + kbeg);
    uint4 vb1 = *(const uint4*)(gB + (size_t)32 * K + kbeg);
    for (int k0 = kbeg; k0 < kend; k0 += 64) {
        __syncthreads();
        *(uint4*)&As[wAb]        = va0;
        *(uint4*)&As[wAb + 2048] = va1;
        *(uint4*)&As[wAb + 4096] = va2;
        *(uint4*)&As[wAb + 6144] = va3;
        *(uint4*)&Bs[wAb]        = vb0;
        *(uint4*)&Bs[wAb + 2048] = vb1;
        __syncthreads();
        if (k0 + 64 < kend) {
            va0 = *(const uint4*)(gA + k0 + 64);
            va1 = *(const uint4*)(gA + (size_t)32 * K + k0 + 64);
            va2 = *(const uint4*)(gA + (size_t)64 * K + k0 + 64);
            va3 = *(const uint4*)(gA + (size_t)96 * K + k0 + 64);
            vb0 = *(const uint4*)(gB + k0 + 64);
            vb1 = *(const uint4*)(gB + (size_t)32 * K + k0 + 64);
        }
#pragma unroll
        for (int kk = 0; kk < 2; ++kk) {
            const int ks = kk * 4 + hi;      // 0..7
            bf16x8 af[4], bfv[2];
#pragma unroll
            for (int mi = 0; mi < 4; ++mi) {
                int row = wr * 64 + mi * 16 + fr;
                af[mi] = *(const bf16x8*)&As[row * 64 + ((ks ^ (row & 7)) * 8)];
            }
#pragma unroll
            for (int ni = 0; ni < 2; ++ni) {
                int row = wc * 32 + ni * 16 + fr;
                bfv[ni] = *(const bf16x8*)&Bs[row * 64 + ((ks ^ (row & 7)) * 8)];
            }
#pragma unroll
            for (int mi = 0; mi < 4; ++mi)
#pragma unroll
                for (int ni = 0; ni < 2; ++ni)
                    acc[mi][ni] = __builtin_amdgcn_mfma_f32_16x16x32_bf16(
                        af[mi], bfv[ni], acc[mi][ni], 0, 0, 0);
        }
    }
    // epilogue: C/D layout col=lane&15, row=(lane>>4)*4+reg  [m89]
    unsigned short* Cz = Cm + (size_t)bzs * TT * N;
    const int ccol0 = bn + wc * 32 + fr;
    const int crow0 = bm + wr * 64 + hi * 4;
#pragma unroll
    for (int ni = 0; ni < 2; ++ni) {
        int col = ccol0 + ni * 16;
#pragma unroll
        for (int mi = 0; mi < 4; ++mi)
#pragma unroll
            for (int q = 0; q < 4; ++q)
                Cz[(size_t)(crow0 + mi * 16 + q) * N + col] = f2bf(acc[mi][ni][q]);
    }
}

// ---------------------------------------------------------------------------
// Wave-per-row LayerNorm + LeakyReLU: y = y0 + y1 + bias (partials in bf16).
// grid 1024 x 256 thr; wave owns one row, lane covers 8 cols.
__global__ __launch_bounds__(256) void ln_lrelu_kernel(const unsigned short* __restrict__ y0,
                                                       const unsigned short* __restrict__ y1,
                                                       const float* __restrict__ badd,
                                                       const float* __restrict__ g,
                                                       const float* __restrict__ be,
                                                       unsigned short* __restrict__ zb,
                                                       const float* __restrict__ res,
                                                       unsigned short* __restrict__ hbf,
                                                       float* __restrict__ fout) {
    const int lane = threadIdx.x & 63;
    const int row = blockIdx.x * 4 + (threadIdx.x >> 6);
    const size_t base = (size_t)row * 512 + lane * 8;
    const int cb = lane * 8;
    ushort4 ua0 = *(const ushort4*)&y0[base];
    ushort4 ua1 = *(const ushort4*)&y0[base + 4];
    ushort4 ub0 = *(const ushort4*)&y1[base];
    ushort4 ub1 = *(const ushort4*)&y1[base + 4];
    float4 ba = *(const float4*)&badd[cb];
    float4 bb = *(const float4*)&badd[cb + 4];
    float v[8];
    v[0] = bf2f(ua0.x) + bf2f(ub0.x) + ba.x;
    v[1] = bf2f(ua0.y) + bf2f(ub0.y) + ba.y;
    v[2] = bf2f(ua0.z) + bf2f(ub0.z) + ba.z;
    v[3] = bf2f(ua0.w) + bf2f(ub0.w) + ba.w;
    v[4] = bf2f(ua1.x) + bf2f(ub1.x) + bb.x;
    v[5] = bf2f(ua1.y) + bf2f(ub1.y) + bb.y;
    v[6] = bf2f(ua1.z) + bf2f(ub1.z) + bb.z;
    v[7] = bf2f(ua1.w) + bf2f(ub1.w) + bb.w;
    float s = 0.f, ss = 0.f;
#pragma unroll
    for (int j = 0; j < 8; ++j) { s += v[j]; ss += v[j] * v[j]; }
#pragma unroll
    for (int o = 1; o < 64; o <<= 1) {
        s  += __shfl_xor(s, o);
        ss += __shfl_xor(ss, o);
    }
    float m = s * (1.f / 512.f);
    float rs = rsqrtf(ss * (1.f / 512.f) - m * m + LN_EPS);
    float4 ga = *(const float4*)&g[cb];
    float4 gb = *(const float4*)&g[cb + 4];
    float4 ea = *(const float4*)&be[cb];
    float4 eb = *(const float4*)&be[cb + 4];
    float gg[8] = {ga.x, ga.y, ga.z, ga.w, gb.x, gb.y, gb.z, gb.w};
    float ee[8] = {ea.x, ea.y, ea.z, ea.w, eb.x, eb.y, eb.z, eb.w};
    float z[8];
#pragma unroll
    for (int j = 0; j < 8; ++j) {
        float zz = gg[j] * (v[j] - m) * rs + ee[j];
        z[j] = (zz > 0.f) ? zz : NEG_SLOPE * zz;
    }
    if (zb) {
        ushort4 o0, o1;
        o0.x = f2bf(z[0]); o0.y = f2bf(z[1]); o0.z = f2bf(z[2]); o0.w = f2bf(z[3]);
        o1.x = f2bf(z[4]); o1.y = f2bf(z[5]); o1.z = f2bf(z[6]); o1.w = f2bf(z[7]);
        *(ushort4*)&zb[base] = o0;
        *(ushort4*)&zb[base + 4] = o1;
    }
    if (hbf) {
        float4 ra = *(const float4*)&res[base];
        float4 rb2 = *(const float4*)&res[base + 4];
        ushort4 o0, o1;
        o0.x = f2bf(ra.x + z[0]); o0.y = f2bf(ra.y + z[1]);
        o0.z = f2bf(ra.z + z[2]); o0.w = f2bf(ra.w + z[3]);
        o1.x = f2bf(rb2.x + z[4]); o1.y = f2bf(rb2.y + z[5]);
        o1.z = f2bf(rb2.z + z[6]); o1.w = f2bf(rb2.w + z[7]);
        *(ushort4*)&hbf[base] = o0;
        *(ushort4*)&hbf[base + 4] = o1;
    }
    if (fout) {
        *(float4*)&fout[base] = make_float4(z[0], z[1], z[2], z[3]);
        *(float4*)&fout[base + 4] = make_float4(z[4], z[5], z[6], z[7]);
    }
}

// ---------------------------------------------------------------------------
extern "C" void kernel_launch(void* const* d_in, const int* in_sizes, int n_in,
                              void* d_out, int out_size, void* d_ws, size_t ws_size,
                              hipStream_t stream) {
    const float* x     = (const float*)d_in[0];
    const int*   start = (const int*)d_in[1];
    const float* s0r = (const float*)d_in[3];
    const float* s0i = (const float*)d_in[4];
    const float* Wt  = (const float*)d_in[5];
    const float* Wc  = (const float*)d_in[6];
    const float* a   = (const float*)d_in[7];
    const float* b   = (const float*)d_in[8];
    const float* W0  = (const float*)d_in[9];
    const float* b0  = (const float*)d_in[10];
    const float* g0  = (const float*)d_in[11];
    const float* be0 = (const float*)d_in[12];
    const float* W1  = (const float*)d_in[13];
    const float* b1  = (const float*)d_in[14];
    const float* g1  = (const float*)d_in[15];
    const float* be1 = (const float*)d_in[16];
    float* out = (float*)d_out;
    float* ws  = (float*)d_ws;

    // workspace layout (float-unit offsets, all 16B aligned)  ~44 MB
    float* p = ws;
    float* tcabs  = p; p += 262144;                  // [4096][64] f32 (invd folded)
    float4* ab4   = (float4*)p; p += 524288;         // [128][1024] float4
    unsigned short* scaled = (unsigned short*)p; p += 4194304;   // [4096][2048] bf16
    unsigned short* ybufp_bf = (unsigned short*)p; p += 2097152; // [2][4096][512] bf16 partials
    unsigned short* zbuf_bf = (unsigned short*)p; p += 1048576;  // [4096][512] bf16
    unsigned short* x_bf    = (unsigned short*)p; p += 1048576;
    unsigned short* h_bf    = (unsigned short*)p; p += 1048576;
    unsigned short* Wtcbf   = (unsigned short*)p; p += 32768;    // [2][64][512] bf16
    unsigned short* W0bf    = (unsigned short*)p; p += 1048576;  // [2][512][2048] bf16
    unsigned short* W1bf    = (unsigned short*)p; p += 262144;   // [2][512][512] bf16

    setup_kernel<<<(NCV + NPK + 255) / 256, 256, 0, stream>>>(
        (const float4*)x, (const float4*)W0, (const float4*)W1, Wt, Wc,
        (ushort4*)x_bf, (ushort4*)W0bf, (ushort4*)W1bf, (ushort4*)Wtcbf);

    for (int i = 0; i < LL; ++i) {
        const unsigned short* hb = (i == 0) ? x_bf : h_bf;
        proj_denom_kernel<<<64, 256, 0, stream>>>(
            hb, Wtcbf + (size_t)i * 64 * 512, tcabs);
        scan_pass1<<<NCHUNK * RC / 256, 256, 0, stream>>>(
            tcabs, start, a + i * RR, b + i * CC, ab4);
        scan_pass2f<<<NCHUNK * 4, 256, 0, stream>>>(
            tcabs, ab4, start, a + i * RR, b + i * CC,
            s0r + i * RC, s0i + i * RC, scaled);
        gemm_bt_mfma<2048, 512, 2><<<dim3(8, 32, 2), 256, 0, stream>>>(
            scaled, W0bf + (size_t)i * 512 * 2048, ybufp_bf);
        ln_lrelu_kernel<<<1024, 256, 0, stream>>>(
            ybufp_bf, ybufp_bf + (size_t)TT * 512, b0 + i * DD, g0 + i * DD, be0 + i * DD,
            zbuf_bf, nullptr, nullptr, nullptr);
        gemm_bt_mfma<512, 512, 2><<<dim3(8, 32, 2), 256, 0, stream>>>(
            zbuf_bf, W1bf + (size_t)i * 512 * 512, ybufp_bf);
        ln_lrelu_kernel<<<1024, 256, 0, stream>>>(
            ybufp_bf, ybufp_bf + (size_t)TT * 512, b1 + i * DD, g1 + i * DD, be1 + i * DD,
            nullptr,
            (i < LL - 1) ? x : nullptr,
            (i < LL - 1) ? h_bf : nullptr,
            (i == LL - 1) ? out : nullptr);
    }
}